// Round 3
// baseline (784.889 us; speedup 1.0000x reference)
//
#include <hip/hip_runtime.h>

typedef short bf16x8 __attribute__((ext_vector_type(8)));
typedef float f32x4 __attribute__((ext_vector_type(4)));
typedef unsigned short u16;

#define NB 8
#define NS 1024
#define NE 768
#define NH 12
#define ND 64
#define QSCALE 0.18033688011112042f   // 0.125 * log2(e): scores land in log2 domain

__device__ __forceinline__ u16 f2bf(float f){
  unsigned u = __float_as_uint(f);
  u += 0x7fffu + ((u >> 16) & 1u);
  return (u16)(u >> 16);
}

// pack two fp32 -> two bf16 (round-half-up) in one u32 via v_perm
__device__ __forceinline__ unsigned pack2bf(float a, float b){
  unsigned ua = __float_as_uint(a) + 0x8000u;
  unsigned ub = __float_as_uint(b) + 0x8000u;
  return __builtin_amdgcn_perm(ub, ua, 0x07060302u);
}

#define EXP2(x) __builtin_amdgcn_exp2f(x)

// ---------------- fused fp32 -> bf16 convert (x, Wqkv, out_w in one launch) ----------------
__global__ void cvt3_kernel(const float* __restrict__ s0, const float* __restrict__ s1,
                            const float* __restrict__ s2,
                            u16* __restrict__ d0, u16* __restrict__ d1, u16* __restrict__ d2){
  const int n0 = 1572864, n1 = 442368, n2 = 147456;   // float4 counts
  int i = blockIdx.x * 256 + threadIdx.x;
  const float* s; u16* d; int j;
  if (i < n0){ s = s0; d = d0; j = i; }
  else if (i < n0 + n1){ s = s1; d = d1; j = i - n0; }
  else { s = s2; d = d2; j = i - n0 - n1; }
  float4 v = ((const float4*)s)[j];
  ushort4 o;
  o.x = f2bf(v.x); o.y = f2bf(v.y); o.z = f2bf(v.z); o.w = f2bf(v.w);
  ((ushort4*)d)[j] = o;
}

// ---------------- lengths from prefix mask (dtype auto-detect) ----------------
__global__ void lengths_kernel(const unsigned int* __restrict__ mi, int* __restrict__ lens){
  __shared__ int isByte;
  int tid = threadIdx.x;
  int any = 0;
  for (int i = tid; i < 2048; i += 512) any |= (mi[i] > 1u) ? 1 : 0;
  if (tid == 0) isByte = 0;
  __syncthreads();
  if (any) atomicOr(&isByte, 1);
  __syncthreads();
  int byteMode = isByte;
  int b = tid >> 6, lane = tid & 63;
  int cnt = 0;
  if (byteMode){
    const unsigned char* p = (const unsigned char*)mi;
    for (int j = 0; j < 16; ++j) cnt += p[b*NS + j*64 + lane] ? 1 : 0;
  } else {
    for (int j = 0; j < 16; ++j) cnt += mi[b*NS + j*64 + lane] ? 1 : 0;
  }
  for (int o = 1; o < 64; o <<= 1) cnt += __shfl_xor(cnt, o, 64);
  if (lane == 0) lens[b] = cnt;
}

// LDS row stride: 32 bf16 data + 8 pad = 40 u16 = 80 B (16B-aligned, 2-way banks = free)
#define LROW 40

// ---------------- QKV projection GEMM: [8192,768] x [2304,768]^T ----------------
// reg-prefetch pipeline; per-block operand swap so epilogue stores are 8B-packed
__global__ __launch_bounds__(256, 4) void gemm_qkv(
    const u16* __restrict__ A, const u16* __restrict__ Bw,
    const float* __restrict__ bias,
    u16* __restrict__ qb, u16* __restrict__ kb, u16* __restrict__ vb)
{
  __shared__ __align__(16) u16 smA[128*LROW];
  __shared__ __align__(16) u16 smB[128*LROW];
  const int tid = threadIdx.x;
  const int lane = tid & 63;
  const int wave = tid >> 6;
  const int quad = lane >> 4, l16 = lane & 15;
  const int wm = wave >> 1, wn = wave & 1;
  const int m0 = blockIdx.y * 128;
  const int n0 = blockIdx.x * 128;
  const int which = blockIdx.x / 6;        // 0=q, 1=k, 2=v (uniform per block)

  // staging: thread covers (row=tid>>2, 16B chunk tid&3) for rows r and r+64
  const int srow = tid >> 2;
  const int soff = (tid & 3) * 16;
  const char* gA = (const char*)A + ((size_t)(m0 + srow)*NE)*2 + soff;
  const char* gB = (const char*)Bw + ((size_t)(n0 + srow)*NE)*2 + soff;
  uint4 a0 = *(const uint4*)(gA);
  uint4 a1 = *(const uint4*)(gA + (size_t)64*NE*2);
  uint4 b0 = *(const uint4*)(gB);
  uint4 b1 = *(const uint4*)(gB + (size_t)64*NE*2);
  char* lA = (char*)smA + srow*(LROW*2) + soff;
  char* lB = (char*)smB + srow*(LROW*2) + soff;

  f32x4 acc[4][4] = {};

  for (int kt = 0; kt < NE; kt += 32){
    __syncthreads();                 // prior readers done; no vmcnt wait here
    *(uint4*)lA = a0; *(uint4*)(lA + 64*LROW*2) = a1;
    *(uint4*)lB = b0; *(uint4*)(lB + 64*LROW*2) = b1;
    __syncthreads();
    if (kt + 32 < NE){               // prefetch next kt into regs (drained next iter)
      const char* nA = gA + (kt + 32)*2;
      const char* nB = gB + (kt + 32)*2;
      a0 = *(const uint4*)nA; a1 = *(const uint4*)(nA + (size_t)64*NE*2);
      b0 = *(const uint4*)nB; b1 = *(const uint4*)(nB + (size_t)64*NE*2);
    }
    bf16x8 av[4], bv[4];
    #pragma unroll
    for (int i = 0; i < 4; ++i){
      av[i] = *(const bf16x8*)&smA[(wm*64 + i*16 + l16)*LROW + quad*8];
      bv[i] = *(const bf16x8*)&smB[(wn*64 + i*16 + l16)*LROW + quad*8];
    }
    if (which < 2){
      #pragma unroll
      for (int mi = 0; mi < 4; ++mi)
        #pragma unroll
        for (int ni = 0; ni < 4; ++ni)
          acc[mi][ni] = __builtin_amdgcn_mfma_f32_16x16x32_bf16(bv[ni], av[mi], acc[mi][ni], 0, 0, 0);
    } else {
      #pragma unroll
      for (int mi = 0; mi < 4; ++mi)
        #pragma unroll
        for (int ni = 0; ni < 4; ++ni)
          acc[mi][ni] = __builtin_amdgcn_mfma_f32_16x16x32_bf16(av[mi], bv[ni], acc[mi][ni], 0, 0, 0);
    }
  }

  if (which < 2){
    // swapped: m on l16, n on (quad,r) -> 4 consecutive d per lane
    u16* dst = (which == 0) ? qb : kb;
    const float sc = (which == 0) ? QSCALE : 1.0f;
    #pragma unroll
    for (int ni = 0; ni < 4; ++ni){
      int gcol0 = n0 + wn*64 + ni*16 + quad*4;
      int rem = gcol0 - which*NE;
      int hh = rem >> 6, dd0 = rem & 63;
      float4 b4 = *(const float4*)&bias[gcol0];
      #pragma unroll
      for (int mi = 0; mi < 4; ++mi){
        int grow = m0 + wm*64 + mi*16 + l16;
        int bb = grow >> 10, ss = grow & 1023;
        int bh = bb*NH + hh;
        float v0 = (acc[mi][ni][0] + b4.x)*sc, v1 = (acc[mi][ni][1] + b4.y)*sc;
        float v2 = (acc[mi][ni][2] + b4.z)*sc, v3 = (acc[mi][ni][3] + b4.w)*sc;
        uint2 pr; pr.x = pack2bf(v0, v1); pr.y = pack2bf(v2, v3);
        *(uint2*)&dst[((size_t)bh*NS + ss)*ND + dd0] = pr;
      }
    }
  } else {
    // normal: n on l16, m(=s) on (quad,r) -> 4 consecutive s per lane in (b,h,d,s)
    #pragma unroll
    for (int ni = 0; ni < 4; ++ni){
      int gcol = n0 + wn*64 + ni*16 + l16;
      int rem = gcol - 2*NE;
      int hh = rem >> 6, dd = rem & 63;
      float bval = bias[gcol];
      #pragma unroll
      for (int mi = 0; mi < 4; ++mi){
        int grow0 = m0 + wm*64 + mi*16 + quad*4;
        int bb = grow0 >> 10, ss0 = grow0 & 1023;
        int bh = bb*NH + hh;
        float v0 = acc[mi][ni][0] + bval, v1 = acc[mi][ni][1] + bval;
        float v2 = acc[mi][ni][2] + bval, v3 = acc[mi][ni][3] + bval;
        uint2 pr; pr.x = pack2bf(v0, v1); pr.y = pack2bf(v2, v3);
        *(uint2*)&vb[((size_t)bh*ND + dd)*NS + ss0] = pr;
      }
    }
  }
}

// ---------------- flash attention (S^T form, reg-prefetched K/V, padded LDS) ----------------
__global__ __launch_bounds__(256, 4) void attn_kernel(
    const u16* __restrict__ qb, const u16* __restrict__ kb,
    const u16* __restrict__ vb, const int* __restrict__ lens,
    u16* __restrict__ ctx)
{
  __shared__ __align__(16) u16 smQ[2][64*LROW];
  __shared__ __align__(16) u16 smK[2][64*LROW];
  __shared__ __align__(16) u16 smV[2][64*LROW];
  __shared__ __align__(16) u16 smP[4][16*72];

  const int tid = threadIdx.x, lane = tid & 63, wave = tid >> 6;
  const int quad = lane >> 4, l16 = lane & 15;
  const int bh = blockIdx.y;
  const int b = bh / NH;
  const int h = bh - b*NH;
  const int q0 = blockIdx.x * 64;
  const int len = lens[b];

  const int r0 = tid >> 2;
  const int ch = (tid & 3) * 16;

  // Q tile: global -> regs -> padded LDS (written before first barrier pair)
  {
    const char* gq = (const char*)qb + (size_t)(bh*NS + q0 + r0)*128 + ch;
    uint4 qp0 = *(const uint4*)(gq);
    uint4 qp1 = *(const uint4*)(gq + 64);
    *(uint4*)((char*)smQ[0] + r0*(LROW*2) + ch) = qp0;
    *(uint4*)((char*)smQ[1] + r0*(LROW*2) + ch) = qp1;
  }

  // K/V register prefetch (tile 0)
  const char* gk = (const char*)kb + ((size_t)bh*NS + r0)*128 + ch;
  const char* gv = (const char*)vb + ((size_t)(bh*ND + r0))*(NS*2) + ch;
  uint4 kp0 = *(const uint4*)(gk);
  uint4 kp1 = *(const uint4*)(gk + 64);
  uint4 vp0 = *(const uint4*)(gv);
  uint4 vp1 = *(const uint4*)(gv + 64);

  char* wK0 = (char*)smK[0] + r0*(LROW*2) + ch;
  char* wK1 = (char*)smK[1] + r0*(LROW*2) + ch;
  char* wV0 = (char*)smV[0] + r0*(LROW*2) + ch;
  char* wV1 = (char*)smV[1] + r0*(LROW*2) + ch;

  float m_i = -1e30f, l_i = 0.f;
  f32x4 accO[4] = {};
  const int ntiles = (len + 63) >> 6;

  for (int t = 0; t < ntiles; ++t){
    __syncthreads();                       // prior readers done
    *(uint4*)wK0 = kp0; *(uint4*)wK1 = kp1;
    *(uint4*)wV0 = vp0; *(uint4*)wV1 = vp1;
    __syncthreads();                       // writes visible
    if (t + 1 < ntiles){                   // prefetch t+1 (drained at next top)
      const char* nk = gk + (size_t)(t+1)*8192;
      const char* nv = gv + (size_t)(t+1)*128;
      kp0 = *(const uint4*)(nk); kp1 = *(const uint4*)(nk + 64);
      vp0 = *(const uint4*)(nv); vp1 = *(const uint4*)(nv + 64);
    }

    // S^T = K_tile . Q^T  (per wave: 64 keys x 16 q-rows)
    f32x4 accS[4] = {};
    #pragma unroll
    for (int kc = 0; kc < 2; ++kc){
      bf16x8 bq = *(const bf16x8*)&smQ[kc][(wave*16 + l16)*LROW + quad*8];
      #pragma unroll
      for (int ni = 0; ni < 4; ++ni){
        bf16x8 ak = *(const bf16x8*)&smK[kc][(ni*16 + l16)*LROW + quad*8];
        accS[ni] = __builtin_amdgcn_mfma_f32_16x16x32_bf16(ak, bq, accS[ni], 0, 0, 0);
      }
    }

    // online softmax: lane owns q-row (l16); keys = key0 + ni*16 + quad*4 + r
    int key0 = t*64;
    float mx = -3e38f;
    #pragma unroll
    for (int ni = 0; ni < 4; ++ni)
      #pragma unroll
      for (int r = 0; r < 4; ++r){
        int key = key0 + ni*16 + quad*4 + r;
        float x = (key < len) ? accS[ni][r] : -1e30f;
        accS[ni][r] = x;
        mx = fmaxf(mx, x);
      }
    mx = fmaxf(mx, __shfl_xor(mx, 16, 64));
    mx = fmaxf(mx, __shfl_xor(mx, 32, 64));
    float mnew = fmaxf(m_i, mx);
    float alpha = EXP2(m_i - mnew);
    float sum = 0.f;
    char* pRow = (char*)&smP[wave][0] + l16*144;
    #pragma unroll
    for (int ni = 0; ni < 4; ++ni){
      float p0 = EXP2(accS[ni][0] - mnew);
      float p1 = EXP2(accS[ni][1] - mnew);
      float p2 = EXP2(accS[ni][2] - mnew);
      float p3 = EXP2(accS[ni][3] - mnew);
      sum += (p0 + p1) + (p2 + p3);
      uint2 pr; pr.x = pack2bf(p0, p1); pr.y = pack2bf(p2, p3);
      *(uint2*)(pRow + ni*32 + quad*8) = pr;
    }
    sum += __shfl_xor(sum, 16, 64);
    sum += __shfl_xor(sum, 32, 64);
    l_i = l_i * alpha + sum;
    m_i = mnew;
    #pragma unroll
    for (int di = 0; di < 4; ++di) accO[di] *= alpha;
    asm volatile("s_waitcnt lgkmcnt(0)" ::: "memory");

    // O^T += V^T_tile . P^T
    #pragma unroll
    for (int kc = 0; kc < 2; ++kc){
      bf16x8 bp = *(const bf16x8*)(pRow + kc*64 + quad*16);
      #pragma unroll
      for (int di = 0; di < 4; ++di){
        bf16x8 av = *(const bf16x8*)&smV[kc][(di*16 + l16)*LROW + quad*8];
        accO[di] = __builtin_amdgcn_mfma_f32_16x16x32_bf16(av, bp, accO[di], 0, 0, 0);
      }
    }
  }

  // epilogue: lane owns q-row; d = di*16 + quad*4 + r (4 consecutive -> b64 store)
  int q = q0 + wave*16 + l16;
  float inv = (q < len) ? (1.0f / l_i) : 0.f;
  size_t base = (size_t)(b*NS + q)*NE + h*ND;
  #pragma unroll
  for (int di = 0; di < 4; ++di){
    float v0 = accO[di][0]*inv, v1 = accO[di][1]*inv;
    float v2 = accO[di][2]*inv, v3 = accO[di][3]*inv;
    uint2 pr; pr.x = pack2bf(v0, v1); pr.y = pack2bf(v2, v3);
    *(uint2*)&ctx[base + di*16 + quad*4] = pr;
  }
}

// ---------------- output projection GEMM: [8192,768] x [768,768]^T -> fp32 ----------------
// always operand-swapped: epilogue = float4 stores
__global__ __launch_bounds__(256, 4) void gemm_out(
    const u16* __restrict__ A, const u16* __restrict__ Bw,
    const float* __restrict__ bias, float* __restrict__ out)
{
  __shared__ __align__(16) u16 smA[128*LROW];
  __shared__ __align__(16) u16 smB[128*LROW];
  const int tid = threadIdx.x;
  const int lane = tid & 63;
  const int wave = tid >> 6;
  const int quad = lane >> 4, l16 = lane & 15;
  const int wm = wave >> 1, wn = wave & 1;
  const int m0 = blockIdx.y * 128;
  const int n0 = blockIdx.x * 128;

  const int srow = tid >> 2;
  const int soff = (tid & 3) * 16;
  const char* gA = (const char*)A + ((size_t)(m0 + srow)*NE)*2 + soff;
  const char* gB = (const char*)Bw + ((size_t)(n0 + srow)*NE)*2 + soff;
  uint4 a0 = *(const uint4*)(gA);
  uint4 a1 = *(const uint4*)(gA + (size_t)64*NE*2);
  uint4 b0 = *(const uint4*)(gB);
  uint4 b1 = *(const uint4*)(gB + (size_t)64*NE*2);
  char* lA = (char*)smA + srow*(LROW*2) + soff;
  char* lB = (char*)smB + srow*(LROW*2) + soff;

  f32x4 acc[4][4] = {};

  for (int kt = 0; kt < NE; kt += 32){
    __syncthreads();
    *(uint4*)lA = a0; *(uint4*)(lA + 64*LROW*2) = a1;
    *(uint4*)lB = b0; *(uint4*)(lB + 64*LROW*2) = b1;
    __syncthreads();
    if (kt + 32 < NE){
      const char* nA = gA + (kt + 32)*2;
      const char* nB = gB + (kt + 32)*2;
      a0 = *(const uint4*)nA; a1 = *(const uint4*)(nA + (size_t)64*NE*2);
      b0 = *(const uint4*)nB; b1 = *(const uint4*)(nB + (size_t)64*NE*2);
    }
    bf16x8 av[4], bv[4];
    #pragma unroll
    for (int i = 0; i < 4; ++i){
      av[i] = *(const bf16x8*)&smA[(wm*64 + i*16 + l16)*LROW + quad*8];
      bv[i] = *(const bf16x8*)&smB[(wn*64 + i*16 + l16)*LROW + quad*8];
    }
    #pragma unroll
    for (int mi = 0; mi < 4; ++mi)
      #pragma unroll
      for (int ni = 0; ni < 4; ++ni)
        acc[mi][ni] = __builtin_amdgcn_mfma_f32_16x16x32_bf16(bv[ni], av[mi], acc[mi][ni], 0, 0, 0);
  }

  #pragma unroll
  for (int ni = 0; ni < 4; ++ni){
    int gcol0 = n0 + wn*64 + ni*16 + quad*4;
    float4 b4 = *(const float4*)&bias[gcol0];
    #pragma unroll
    for (int mi = 0; mi < 4; ++mi){
      int grow = m0 + wm*64 + mi*16 + l16;
      float4 o;
      o.x = acc[mi][ni][0] + b4.x; o.y = acc[mi][ni][1] + b4.y;
      o.z = acc[mi][ni][2] + b4.z; o.w = acc[mi][ni][3] + b4.w;
      *(float4*)&out[(size_t)grow*NE + gcol0] = o;
    }
  }
}

extern "C" void kernel_launch(void* const* d_in, const int* in_sizes, int n_in,
                              void* d_out, int out_size, void* d_ws, size_t ws_size,
                              hipStream_t stream)
{
  const float* x    = (const float*)d_in[0];
  const void*  mask = d_in[1];
  const float* wqkv = (const float*)d_in[2];
  const float* bqkv = (const float*)d_in[3];
  const float* wout = (const float*)d_in[4];
  const float* bout = (const float*)d_in[5];

  char* ws = (char*)d_ws;
  u16* xb    = (u16*)(ws + 0);
  u16* wqkvb = (u16*)(ws + 12582912);
  u16* woutb = (u16*)(ws + 16121856);
  u16* qbuf  = (u16*)(ws + 17301504);
  u16* kbuf  = (u16*)(ws + 29884416);
  u16* vbuf  = (u16*)(ws + 42467328);
  u16* ctxb  = (u16*)(ws + 55050240);
  int* lens  = (int*)(ws + 67633152);

  cvt3_kernel<<<8448, 256, 0, stream>>>(x, wqkv, wout, xb, wqkvb, woutb);
  lengths_kernel<<<1, 512, 0, stream>>>((const unsigned int*)mask, lens);
  gemm_qkv<<<dim3(18, 64), 256, 0, stream>>>(xb, wqkvb, bqkv, qbuf, kbuf, vbuf);
  attn_kernel<<<dim3(16, 96), 256, 0, stream>>>(qbuf, kbuf, vbuf, lens, ctxb);
  gemm_out<<<dim3(6, 64), 256, 0, stream>>>(ctxb, woutb, bout, (float*)d_out);
}

// Round 4
// 223.439 us; speedup vs baseline: 3.5128x; 3.5128x over previous
//
#include <hip/hip_runtime.h>

typedef short bf16x8 __attribute__((ext_vector_type(8)));
typedef float f32x4 __attribute__((ext_vector_type(4)));
typedef unsigned short u16;

#define NB 8
#define NS 1024
#define NE 768
#define NH 12
#define ND 64
#define QSCALE 0.18033688011112042f   // 0.125 * log2(e): scores land in log2 domain

__device__ __forceinline__ u16 f2bf(float f){
  unsigned u = __float_as_uint(f);
  u += 0x7fffu + ((u >> 16) & 1u);
  return (u16)(u >> 16);
}

// pack two fp32 -> two bf16 (round-half-up) in one u32 via v_perm
__device__ __forceinline__ unsigned pack2bf(float a, float b){
  unsigned ua = __float_as_uint(a) + 0x8000u;
  unsigned ub = __float_as_uint(b) + 0x8000u;
  return __builtin_amdgcn_perm(ub, ua, 0x07060302u);
}

#define EXP2(x) __builtin_amdgcn_exp2f(x)

// ---------------- fused fp32 -> bf16 convert (x, Wqkv, out_w in one launch) ----------------
__global__ void cvt3_kernel(const float* __restrict__ s0, const float* __restrict__ s1,
                            const float* __restrict__ s2,
                            u16* __restrict__ d0, u16* __restrict__ d1, u16* __restrict__ d2){
  const int n0 = 1572864, n1 = 442368, n2 = 147456;   // float4 counts
  int i = blockIdx.x * 256 + threadIdx.x;
  const float* s; u16* d; int j;
  if (i < n0){ s = s0; d = d0; j = i; }
  else if (i < n0 + n1){ s = s1; d = d1; j = i - n0; }
  else { s = s2; d = d2; j = i - n0 - n1; }
  float4 v = ((const float4*)s)[j];
  ushort4 o;
  o.x = f2bf(v.x); o.y = f2bf(v.y); o.z = f2bf(v.z); o.w = f2bf(v.w);
  ((ushort4*)d)[j] = o;
}

// ---------------- lengths from prefix mask (dtype auto-detect) ----------------
__global__ void lengths_kernel(const unsigned int* __restrict__ mi, int* __restrict__ lens){
  __shared__ int isByte;
  int tid = threadIdx.x;
  int any = 0;
  for (int i = tid; i < 2048; i += 512) any |= (mi[i] > 1u) ? 1 : 0;
  if (tid == 0) isByte = 0;
  __syncthreads();
  if (any) atomicOr(&isByte, 1);
  __syncthreads();
  int byteMode = isByte;
  int b = tid >> 6, lane = tid & 63;
  int cnt = 0;
  if (byteMode){
    const unsigned char* p = (const unsigned char*)mi;
    for (int j = 0; j < 16; ++j) cnt += p[b*NS + j*64 + lane] ? 1 : 0;
  } else {
    for (int j = 0; j < 16; ++j) cnt += mi[b*NS + j*64 + lane] ? 1 : 0;
  }
  for (int o = 1; o < 64; o <<= 1) cnt += __shfl_xor(cnt, o, 64);
  if (lane == 0) lens[b] = cnt;
}

// LDS row stride: 32 bf16 data + 8 pad = 40 u16 = 80 B (16B-aligned, 2-way banks = free)
#define LROW 40

// ---------------- QKV projection GEMM: [8192,768] x [2304,768]^T ----------------
// reg-prefetch pipeline; per-block operand swap so epilogue stores are 8B-packed
// launch_bounds(256,2): 256-reg unified budget — (256,4) spilled (R3: 2.7GB scratch traffic)
__global__ __launch_bounds__(256, 2) void gemm_qkv(
    const u16* __restrict__ A, const u16* __restrict__ Bw,
    const float* __restrict__ bias,
    u16* __restrict__ qb, u16* __restrict__ kb, u16* __restrict__ vb)
{
  __shared__ __align__(16) u16 smA[128*LROW];
  __shared__ __align__(16) u16 smB[128*LROW];
  const int tid = threadIdx.x;
  const int lane = tid & 63;
  const int wave = tid >> 6;
  const int quad = lane >> 4, l16 = lane & 15;
  const int wm = wave >> 1, wn = wave & 1;
  const int m0 = blockIdx.y * 128;
  const int n0 = blockIdx.x * 128;
  const int which = blockIdx.x / 6;        // 0=q, 1=k, 2=v (uniform per block)

  // staging: thread covers (row=tid>>2, 16B chunk tid&3) for rows r and r+64
  const int srow = tid >> 2;
  const int soff = (tid & 3) * 16;
  const char* gA = (const char*)A + ((size_t)(m0 + srow)*NE)*2 + soff;
  const char* gB = (const char*)Bw + ((size_t)(n0 + srow)*NE)*2 + soff;
  uint4 a0 = *(const uint4*)(gA);
  uint4 a1 = *(const uint4*)(gA + (size_t)64*NE*2);
  uint4 b0 = *(const uint4*)(gB);
  uint4 b1 = *(const uint4*)(gB + (size_t)64*NE*2);
  char* lA = (char*)smA + srow*(LROW*2) + soff;
  char* lB = (char*)smB + srow*(LROW*2) + soff;

  f32x4 acc[4][4] = {};

  for (int kt = 0; kt < NE; kt += 32){
    __syncthreads();                 // prior readers done; no vmcnt wait here
    *(uint4*)lA = a0; *(uint4*)(lA + 64*LROW*2) = a1;
    *(uint4*)lB = b0; *(uint4*)(lB + 64*LROW*2) = b1;
    __syncthreads();
    if (kt + 32 < NE){               // prefetch next kt into regs (drained next iter)
      const char* nA = gA + (kt + 32)*2;
      const char* nB = gB + (kt + 32)*2;
      a0 = *(const uint4*)nA; a1 = *(const uint4*)(nA + (size_t)64*NE*2);
      b0 = *(const uint4*)nB; b1 = *(const uint4*)(nB + (size_t)64*NE*2);
    }
    bf16x8 av[4], bv[4];
    #pragma unroll
    for (int i = 0; i < 4; ++i){
      av[i] = *(const bf16x8*)&smA[(wm*64 + i*16 + l16)*LROW + quad*8];
      bv[i] = *(const bf16x8*)&smB[(wn*64 + i*16 + l16)*LROW + quad*8];
    }
    if (which < 2){
      #pragma unroll
      for (int mi = 0; mi < 4; ++mi)
        #pragma unroll
        for (int ni = 0; ni < 4; ++ni)
          acc[mi][ni] = __builtin_amdgcn_mfma_f32_16x16x32_bf16(bv[ni], av[mi], acc[mi][ni], 0, 0, 0);
    } else {
      #pragma unroll
      for (int mi = 0; mi < 4; ++mi)
        #pragma unroll
        for (int ni = 0; ni < 4; ++ni)
          acc[mi][ni] = __builtin_amdgcn_mfma_f32_16x16x32_bf16(av[mi], bv[ni], acc[mi][ni], 0, 0, 0);
    }
  }

  if (which < 2){
    // swapped: m on l16, n on (quad,r) -> 4 consecutive d per lane
    u16* dst = (which == 0) ? qb : kb;
    const float sc = (which == 0) ? QSCALE : 1.0f;
    #pragma unroll
    for (int ni = 0; ni < 4; ++ni){
      int gcol0 = n0 + wn*64 + ni*16 + quad*4;
      int rem = gcol0 - which*NE;
      int hh = rem >> 6, dd0 = rem & 63;
      float4 b4 = *(const float4*)&bias[gcol0];
      #pragma unroll
      for (int mi = 0; mi < 4; ++mi){
        int grow = m0 + wm*64 + mi*16 + l16;
        int bb = grow >> 10, ss = grow & 1023;
        int bh = bb*NH + hh;
        float v0 = (acc[mi][ni][0] + b4.x)*sc, v1 = (acc[mi][ni][1] + b4.y)*sc;
        float v2 = (acc[mi][ni][2] + b4.z)*sc, v3 = (acc[mi][ni][3] + b4.w)*sc;
        uint2 pr; pr.x = pack2bf(v0, v1); pr.y = pack2bf(v2, v3);
        *(uint2*)&dst[((size_t)bh*NS + ss)*ND + dd0] = pr;
      }
    }
  } else {
    // normal: n on l16, m(=s) on (quad,r) -> 4 consecutive s per lane in (b,h,d,s)
    #pragma unroll
    for (int ni = 0; ni < 4; ++ni){
      int gcol = n0 + wn*64 + ni*16 + l16;
      int rem = gcol - 2*NE;
      int hh = rem >> 6, dd = rem & 63;
      float bval = bias[gcol];
      #pragma unroll
      for (int mi = 0; mi < 4; ++mi){
        int grow0 = m0 + wm*64 + mi*16 + quad*4;
        int bb = grow0 >> 10, ss0 = grow0 & 1023;
        int bh = bb*NH + hh;
        float v0 = acc[mi][ni][0] + bval, v1 = acc[mi][ni][1] + bval;
        float v2 = acc[mi][ni][2] + bval, v3 = acc[mi][ni][3] + bval;
        uint2 pr; pr.x = pack2bf(v0, v1); pr.y = pack2bf(v2, v3);
        *(uint2*)&vb[((size_t)bh*ND + dd)*NS + ss0] = pr;
      }
    }
  }
}

// ---------------- flash attention (S^T form, reg-prefetched K/V, padded LDS) ----------------
__global__ __launch_bounds__(256, 4) void attn_kernel(
    const u16* __restrict__ qb, const u16* __restrict__ kb,
    const u16* __restrict__ vb, const int* __restrict__ lens,
    u16* __restrict__ ctx)
{
  __shared__ __align__(16) u16 smQ[2][64*LROW];
  __shared__ __align__(16) u16 smK[2][64*LROW];
  __shared__ __align__(16) u16 smV[2][64*LROW];
  __shared__ __align__(16) u16 smP[4][16*72];

  const int tid = threadIdx.x, lane = tid & 63, wave = tid >> 6;
  const int quad = lane >> 4, l16 = lane & 15;
  const int bh = blockIdx.y;
  const int b = bh / NH;
  const int h = bh - b*NH;
  const int q0 = blockIdx.x * 64;
  const int len = lens[b];

  const int r0 = tid >> 2;
  const int ch = (tid & 3) * 16;

  // Q tile: global -> regs -> padded LDS (written before first barrier pair)
  {
    const char* gq = (const char*)qb + (size_t)(bh*NS + q0 + r0)*128 + ch;
    uint4 qp0 = *(const uint4*)(gq);
    uint4 qp1 = *(const uint4*)(gq + 64);
    *(uint4*)((char*)smQ[0] + r0*(LROW*2) + ch) = qp0;
    *(uint4*)((char*)smQ[1] + r0*(LROW*2) + ch) = qp1;
  }

  // K/V register prefetch (tile 0)
  const char* gk = (const char*)kb + ((size_t)bh*NS + r0)*128 + ch;
  const char* gv = (const char*)vb + ((size_t)(bh*ND + r0))*(NS*2) + ch;
  uint4 kp0 = *(const uint4*)(gk);
  uint4 kp1 = *(const uint4*)(gk + 64);
  uint4 vp0 = *(const uint4*)(gv);
  uint4 vp1 = *(const uint4*)(gv + 64);

  char* wK0 = (char*)smK[0] + r0*(LROW*2) + ch;
  char* wK1 = (char*)smK[1] + r0*(LROW*2) + ch;
  char* wV0 = (char*)smV[0] + r0*(LROW*2) + ch;
  char* wV1 = (char*)smV[1] + r0*(LROW*2) + ch;

  float m_i = -1e30f, l_i = 0.f;
  f32x4 accO[4] = {};
  const int ntiles = (len + 63) >> 6;

  for (int t = 0; t < ntiles; ++t){
    __syncthreads();                       // prior readers done
    *(uint4*)wK0 = kp0; *(uint4*)wK1 = kp1;
    *(uint4*)wV0 = vp0; *(uint4*)wV1 = vp1;
    __syncthreads();                       // writes visible
    if (t + 1 < ntiles){                   // prefetch t+1 (drained at next top)
      const char* nk = gk + (size_t)(t+1)*8192;
      const char* nv = gv + (size_t)(t+1)*128;
      kp0 = *(const uint4*)(nk); kp1 = *(const uint4*)(nk + 64);
      vp0 = *(const uint4*)(nv); vp1 = *(const uint4*)(nv + 64);
    }

    // S^T = K_tile . Q^T  (per wave: 64 keys x 16 q-rows)
    f32x4 accS[4] = {};
    #pragma unroll
    for (int kc = 0; kc < 2; ++kc){
      bf16x8 bq = *(const bf16x8*)&smQ[kc][(wave*16 + l16)*LROW + quad*8];
      #pragma unroll
      for (int ni = 0; ni < 4; ++ni){
        bf16x8 ak = *(const bf16x8*)&smK[kc][(ni*16 + l16)*LROW + quad*8];
        accS[ni] = __builtin_amdgcn_mfma_f32_16x16x32_bf16(ak, bq, accS[ni], 0, 0, 0);
      }
    }

    // online softmax: lane owns q-row (l16); keys = key0 + ni*16 + quad*4 + r
    int key0 = t*64;
    float mx = -3e38f;
    #pragma unroll
    for (int ni = 0; ni < 4; ++ni)
      #pragma unroll
      for (int r = 0; r < 4; ++r){
        int key = key0 + ni*16 + quad*4 + r;
        float x = (key < len) ? accS[ni][r] : -1e30f;
        accS[ni][r] = x;
        mx = fmaxf(mx, x);
      }
    mx = fmaxf(mx, __shfl_xor(mx, 16, 64));
    mx = fmaxf(mx, __shfl_xor(mx, 32, 64));
    float mnew = fmaxf(m_i, mx);
    float alpha = EXP2(m_i - mnew);
    float sum = 0.f;
    char* pRow = (char*)&smP[wave][0] + l16*144;
    #pragma unroll
    for (int ni = 0; ni < 4; ++ni){
      float p0 = EXP2(accS[ni][0] - mnew);
      float p1 = EXP2(accS[ni][1] - mnew);
      float p2 = EXP2(accS[ni][2] - mnew);
      float p3 = EXP2(accS[ni][3] - mnew);
      sum += (p0 + p1) + (p2 + p3);
      uint2 pr; pr.x = pack2bf(p0, p1); pr.y = pack2bf(p2, p3);
      *(uint2*)(pRow + ni*32 + quad*8) = pr;
    }
    sum += __shfl_xor(sum, 16, 64);
    sum += __shfl_xor(sum, 32, 64);
    l_i = l_i * alpha + sum;
    m_i = mnew;
    #pragma unroll
    for (int di = 0; di < 4; ++di) accO[di] *= alpha;
    asm volatile("s_waitcnt lgkmcnt(0)" ::: "memory");

    // O^T += V^T_tile . P^T
    #pragma unroll
    for (int kc = 0; kc < 2; ++kc){
      bf16x8 bp = *(const bf16x8*)(pRow + kc*64 + quad*16);
      #pragma unroll
      for (int di = 0; di < 4; ++di){
        bf16x8 av = *(const bf16x8*)&smV[kc][(di*16 + l16)*LROW + quad*8];
        accO[di] = __builtin_amdgcn_mfma_f32_16x16x32_bf16(av, bp, accO[di], 0, 0, 0);
      }
    }
  }

  // epilogue: lane owns q-row; d = di*16 + quad*4 + r (4 consecutive -> b64 store)
  int q = q0 + wave*16 + l16;
  float inv = (q < len) ? (1.0f / l_i) : 0.f;
  size_t base = (size_t)(b*NS + q)*NE + h*ND;
  #pragma unroll
  for (int di = 0; di < 4; ++di){
    float v0 = accO[di][0]*inv, v1 = accO[di][1]*inv;
    float v2 = accO[di][2]*inv, v3 = accO[di][3]*inv;
    uint2 pr; pr.x = pack2bf(v0, v1); pr.y = pack2bf(v2, v3);
    *(uint2*)&ctx[base + di*16 + quad*4] = pr;
  }
}

// ---------------- output projection GEMM: [8192,768] x [768,768]^T -> fp32 ----------------
// always operand-swapped: epilogue = float4 stores. (256,2): see gemm_qkv note.
__global__ __launch_bounds__(256, 2) void gemm_out(
    const u16* __restrict__ A, const u16* __restrict__ Bw,
    const float* __restrict__ bias, float* __restrict__ out)
{
  __shared__ __align__(16) u16 smA[128*LROW];
  __shared__ __align__(16) u16 smB[128*LROW];
  const int tid = threadIdx.x;
  const int lane = tid & 63;
  const int wave = tid >> 6;
  const int quad = lane >> 4, l16 = lane & 15;
  const int wm = wave >> 1, wn = wave & 1;
  const int m0 = blockIdx.y * 128;
  const int n0 = blockIdx.x * 128;

  const int srow = tid >> 2;
  const int soff = (tid & 3) * 16;
  const char* gA = (const char*)A + ((size_t)(m0 + srow)*NE)*2 + soff;
  const char* gB = (const char*)Bw + ((size_t)(n0 + srow)*NE)*2 + soff;
  uint4 a0 = *(const uint4*)(gA);
  uint4 a1 = *(const uint4*)(gA + (size_t)64*NE*2);
  uint4 b0 = *(const uint4*)(gB);
  uint4 b1 = *(const uint4*)(gB + (size_t)64*NE*2);
  char* lA = (char*)smA + srow*(LROW*2) + soff;
  char* lB = (char*)smB + srow*(LROW*2) + soff;

  f32x4 acc[4][4] = {};

  for (int kt = 0; kt < NE; kt += 32){
    __syncthreads();
    *(uint4*)lA = a0; *(uint4*)(lA + 64*LROW*2) = a1;
    *(uint4*)lB = b0; *(uint4*)(lB + 64*LROW*2) = b1;
    __syncthreads();
    if (kt + 32 < NE){
      const char* nA = gA + (kt + 32)*2;
      const char* nB = gB + (kt + 32)*2;
      a0 = *(const uint4*)nA; a1 = *(const uint4*)(nA + (size_t)64*NE*2);
      b0 = *(const uint4*)nB; b1 = *(const uint4*)(nB + (size_t)64*NE*2);
    }
    bf16x8 av[4], bv[4];
    #pragma unroll
    for (int i = 0; i < 4; ++i){
      av[i] = *(const bf16x8*)&smA[(wm*64 + i*16 + l16)*LROW + quad*8];
      bv[i] = *(const bf16x8*)&smB[(wn*64 + i*16 + l16)*LROW + quad*8];
    }
    #pragma unroll
    for (int mi = 0; mi < 4; ++mi)
      #pragma unroll
      for (int ni = 0; ni < 4; ++ni)
        acc[mi][ni] = __builtin_amdgcn_mfma_f32_16x16x32_bf16(bv[ni], av[mi], acc[mi][ni], 0, 0, 0);
  }

  #pragma unroll
  for (int ni = 0; ni < 4; ++ni){
    int gcol0 = n0 + wn*64 + ni*16 + quad*4;
    float4 b4 = *(const float4*)&bias[gcol0];
    #pragma unroll
    for (int mi = 0; mi < 4; ++mi){
      int grow = m0 + wm*64 + mi*16 + l16;
      float4 o;
      o.x = acc[mi][ni][0] + b4.x; o.y = acc[mi][ni][1] + b4.y;
      o.z = acc[mi][ni][2] + b4.z; o.w = acc[mi][ni][3] + b4.w;
      *(float4*)&out[(size_t)grow*NE + gcol0] = o;
    }
  }
}

extern "C" void kernel_launch(void* const* d_in, const int* in_sizes, int n_in,
                              void* d_out, int out_size, void* d_ws, size_t ws_size,
                              hipStream_t stream)
{
  const float* x    = (const float*)d_in[0];
  const void*  mask = d_in[1];
  const float* wqkv = (const float*)d_in[2];
  const float* bqkv = (const float*)d_in[3];
  const float* wout = (const float*)d_in[4];
  const float* bout = (const float*)d_in[5];

  char* ws = (char*)d_ws;
  u16* xb    = (u16*)(ws + 0);
  u16* wqkvb = (u16*)(ws + 12582912);
  u16* woutb = (u16*)(ws + 16121856);
  u16* qbuf  = (u16*)(ws + 17301504);
  u16* kbuf  = (u16*)(ws + 29884416);
  u16* vbuf  = (u16*)(ws + 42467328);
  u16* ctxb  = (u16*)(ws + 55050240);
  int* lens  = (int*)(ws + 67633152);

  cvt3_kernel<<<8448, 256, 0, stream>>>(x, wqkv, wout, xb, wqkvb, woutb);
  lengths_kernel<<<1, 512, 0, stream>>>((const unsigned int*)mask, lens);
  gemm_qkv<<<dim3(18, 64), 256, 0, stream>>>(xb, wqkvb, bqkv, qbuf, kbuf, vbuf);
  attn_kernel<<<dim3(16, 96), 256, 0, stream>>>(qbuf, kbuf, vbuf, lens, ctxb);
  gemm_out<<<dim3(6, 64), 256, 0, stream>>>(ctxb, woutb, bout, (float*)d_out);
}

// Round 5
// 221.948 us; speedup vs baseline: 3.5364x; 1.0067x over previous
//
#include <hip/hip_runtime.h>

typedef short bf16x8 __attribute__((ext_vector_type(8)));
typedef float f32x4 __attribute__((ext_vector_type(4)));
typedef unsigned short u16;

#define NB 8
#define NS 1024
#define NE 768
#define NH 12
#define ND 64
#define QSCALE 0.18033688011112042f   // 0.125 * log2(e): scores land in log2 domain

__device__ __forceinline__ u16 f2bf(float f){
  unsigned u = __float_as_uint(f);
  u += 0x7fffu + ((u >> 16) & 1u);
  return (u16)(u >> 16);
}

// pack two fp32 -> two bf16 (round-half-up) in one u32 via v_perm
__device__ __forceinline__ unsigned pack2bf(float a, float b){
  unsigned ua = __float_as_uint(a) + 0x8000u;
  unsigned ub = __float_as_uint(b) + 0x8000u;
  return __builtin_amdgcn_perm(ub, ua, 0x07060302u);
}

#define EXP2(x) __builtin_amdgcn_exp2f(x)

// ---------------- fused fp32 -> bf16 convert (x, Wqkv, out_w in one launch) ----------------
__global__ void cvt3_kernel(const float* __restrict__ s0, const float* __restrict__ s1,
                            const float* __restrict__ s2,
                            u16* __restrict__ d0, u16* __restrict__ d1, u16* __restrict__ d2){
  const int n0 = 1572864, n1 = 442368, n2 = 147456;   // float4 counts
  int i = blockIdx.x * 256 + threadIdx.x;
  const float* s; u16* d; int j;
  if (i < n0){ s = s0; d = d0; j = i; }
  else if (i < n0 + n1){ s = s1; d = d1; j = i - n0; }
  else { s = s2; d = d2; j = i - n0 - n1; }
  float4 v = ((const float4*)s)[j];
  ushort4 o;
  o.x = f2bf(v.x); o.y = f2bf(v.y); o.z = f2bf(v.z); o.w = f2bf(v.w);
  ((ushort4*)d)[j] = o;
}

// ---------------- lengths from prefix mask (dtype auto-detect) ----------------
__global__ void lengths_kernel(const unsigned int* __restrict__ mi, int* __restrict__ lens){
  __shared__ int isByte;
  int tid = threadIdx.x;
  int any = 0;
  for (int i = tid; i < 2048; i += 512) any |= (mi[i] > 1u) ? 1 : 0;
  if (tid == 0) isByte = 0;
  __syncthreads();
  if (any) atomicOr(&isByte, 1);
  __syncthreads();
  int byteMode = isByte;
  int b = tid >> 6, lane = tid & 63;
  int cnt = 0;
  if (byteMode){
    const unsigned char* p = (const unsigned char*)mi;
    for (int j = 0; j < 16; ++j) cnt += p[b*NS + j*64 + lane] ? 1 : 0;
  } else {
    for (int j = 0; j < 16; ++j) cnt += mi[b*NS + j*64 + lane] ? 1 : 0;
  }
  for (int o = 1; o < 64; o <<= 1) cnt += __shfl_xor(cnt, o, 64);
  if (lane == 0) lens[b] = cnt;
}

// attn LDS row stride: 32 bf16 + 8 pad = 40 u16 = 80 B (granule stride 5: odd -> uniform banks)
#define LROW 40
// gemm LDS row stride (BK=64): 64 bf16 + 8 pad = 72 u16 = 144 B (granule stride 9: odd)
#define LRW 72

// ---------------- QKV projection GEMM: [8192,768] x [2304,768]^T, BK=64 ----------------
// reg-prefetch pipeline (8 uint4), 12 barrier pairs; per-block operand swap for packed stores
// (256,2): 256-reg budget. R3 lesson: (256,4) cap=128 spilled 2.7GB scratch.
__global__ __launch_bounds__(256, 2) void gemm_qkv(
    const u16* __restrict__ A, const u16* __restrict__ Bw,
    const float* __restrict__ bias,
    u16* __restrict__ qb, u16* __restrict__ kb, u16* __restrict__ vb)
{
  __shared__ __align__(16) u16 smA[128*LRW];
  __shared__ __align__(16) u16 smB[128*LRW];
  const int tid = threadIdx.x;
  const int lane = tid & 63;
  const int wave = tid >> 6;
  const int quad = lane >> 4, l16 = lane & 15;
  const int wm = wave >> 1, wn = wave & 1;
  const int m0 = blockIdx.y * 128;
  const int n0 = blockIdx.x * 128;
  const int which = blockIdx.x / 6;        // 0=q, 1=k, 2=v (uniform per block)

  // staging: thread covers rows srow/srow+64, 16B chunks at soff and soff+64 (BK=64 row = 128B)
  const int srow = tid >> 2;
  const int soff = (tid & 3) * 16;
  const char* gA = (const char*)A + ((size_t)(m0 + srow)*NE)*2 + soff;
  const char* gB = (const char*)Bw + ((size_t)(n0 + srow)*NE)*2 + soff;
  uint4 a00 = *(const uint4*)(gA);
  uint4 a01 = *(const uint4*)(gA + 64);
  uint4 a10 = *(const uint4*)(gA + (size_t)64*NE*2);
  uint4 a11 = *(const uint4*)(gA + (size_t)64*NE*2 + 64);
  uint4 b00 = *(const uint4*)(gB);
  uint4 b01 = *(const uint4*)(gB + 64);
  uint4 b10 = *(const uint4*)(gB + (size_t)64*NE*2);
  uint4 b11 = *(const uint4*)(gB + (size_t)64*NE*2 + 64);
  char* lA = (char*)smA + srow*(LRW*2) + soff;
  char* lB = (char*)smB + srow*(LRW*2) + soff;

  f32x4 acc[4][4] = {};

  for (int kt = 0; kt < NE; kt += 64){
    __syncthreads();                 // prior readers done (vmcnt for prefetch drains here)
    *(uint4*)lA = a00; *(uint4*)(lA + 64) = a01;
    *(uint4*)(lA + 64*LRW*2) = a10; *(uint4*)(lA + 64*LRW*2 + 64) = a11;
    *(uint4*)lB = b00; *(uint4*)(lB + 64) = b01;
    *(uint4*)(lB + 64*LRW*2) = b10; *(uint4*)(lB + 64*LRW*2 + 64) = b11;
    __syncthreads();
    if (kt + 64 < NE){               // prefetch next K-tile (hidden behind 32 MFMA)
      const char* nA = gA + (kt + 64)*2;
      const char* nB = gB + (kt + 64)*2;
      a00 = *(const uint4*)nA; a01 = *(const uint4*)(nA + 64);
      a10 = *(const uint4*)(nA + (size_t)64*NE*2); a11 = *(const uint4*)(nA + (size_t)64*NE*2 + 64);
      b00 = *(const uint4*)nB; b01 = *(const uint4*)(nB + 64);
      b10 = *(const uint4*)(nB + (size_t)64*NE*2); b11 = *(const uint4*)(nB + (size_t)64*NE*2 + 64);
    }
    #pragma unroll
    for (int kc = 0; kc < 2; ++kc){
      bf16x8 av[4], bv[4];
      #pragma unroll
      for (int i = 0; i < 4; ++i){
        av[i] = *(const bf16x8*)&smA[(wm*64 + i*16 + l16)*LRW + kc*32 + quad*8];
        bv[i] = *(const bf16x8*)&smB[(wn*64 + i*16 + l16)*LRW + kc*32 + quad*8];
      }
      if (which < 2){
        #pragma unroll
        for (int mi = 0; mi < 4; ++mi)
          #pragma unroll
          for (int ni = 0; ni < 4; ++ni)
            acc[mi][ni] = __builtin_amdgcn_mfma_f32_16x16x32_bf16(bv[ni], av[mi], acc[mi][ni], 0, 0, 0);
      } else {
        #pragma unroll
        for (int mi = 0; mi < 4; ++mi)
          #pragma unroll
          for (int ni = 0; ni < 4; ++ni)
            acc[mi][ni] = __builtin_amdgcn_mfma_f32_16x16x32_bf16(av[mi], bv[ni], acc[mi][ni], 0, 0, 0);
      }
    }
  }

  if (which < 2){
    // swapped: m on l16, n on (quad,r) -> 4 consecutive d per lane
    u16* dst = (which == 0) ? qb : kb;
    const float sc = (which == 0) ? QSCALE : 1.0f;
    #pragma unroll
    for (int ni = 0; ni < 4; ++ni){
      int gcol0 = n0 + wn*64 + ni*16 + quad*4;
      int rem = gcol0 - which*NE;
      int hh = rem >> 6, dd0 = rem & 63;
      float4 b4 = *(const float4*)&bias[gcol0];
      #pragma unroll
      for (int mi = 0; mi < 4; ++mi){
        int grow = m0 + wm*64 + mi*16 + l16;
        int bb = grow >> 10, ss = grow & 1023;
        int bh = bb*NH + hh;
        float v0 = (acc[mi][ni][0] + b4.x)*sc, v1 = (acc[mi][ni][1] + b4.y)*sc;
        float v2 = (acc[mi][ni][2] + b4.z)*sc, v3 = (acc[mi][ni][3] + b4.w)*sc;
        uint2 pr; pr.x = pack2bf(v0, v1); pr.y = pack2bf(v2, v3);
        *(uint2*)&dst[((size_t)bh*NS + ss)*ND + dd0] = pr;
      }
    }
  } else {
    // normal: n on l16, m(=s) on (quad,r) -> 4 consecutive s per lane in (b,h,d,s)
    #pragma unroll
    for (int ni = 0; ni < 4; ++ni){
      int gcol = n0 + wn*64 + ni*16 + l16;
      int rem = gcol - 2*NE;
      int hh = rem >> 6, dd = rem & 63;
      float bval = bias[gcol];
      #pragma unroll
      for (int mi = 0; mi < 4; ++mi){
        int grow0 = m0 + wm*64 + mi*16 + quad*4;
        int bb = grow0 >> 10, ss0 = grow0 & 1023;
        int bh = bb*NH + hh;
        float v0 = acc[mi][ni][0] + bval, v1 = acc[mi][ni][1] + bval;
        float v2 = acc[mi][ni][2] + bval, v3 = acc[mi][ni][3] + bval;
        uint2 pr; pr.x = pack2bf(v0, v1); pr.y = pack2bf(v2, v3);
        *(uint2*)&vb[((size_t)bh*ND + dd)*NS + ss0] = pr;
      }
    }
  }
}

// ---------------- flash attention: Q-tile 128 rows (2 groups), S^T form ----------------
// P row stride 152 B (19 granules, odd -> uniform banks; 144 was 2x-conflicted on b64 writes)
#define PROW 76
__global__ __launch_bounds__(256, 3) void attn_kernel(
    const u16* __restrict__ qb, const u16* __restrict__ kb,
    const u16* __restrict__ vb, const int* __restrict__ lens,
    u16* __restrict__ ctx)
{
  __shared__ __align__(16) u16 smQ[2][128*LROW];
  __shared__ __align__(16) u16 smK[2][64*LROW];
  __shared__ __align__(16) u16 smV[2][64*LROW];
  __shared__ __align__(16) u16 smP[4][16*PROW];

  const int tid = threadIdx.x, lane = tid & 63, wave = tid >> 6;
  const int quad = lane >> 4, l16 = lane & 15;
  const int bh = blockIdx.y;
  const int b = bh / NH;
  const int h = bh - b*NH;
  const int q0 = blockIdx.x * 128;
  const int len = lens[b];

  const int r0 = tid >> 2;
  const int ch = (tid & 3) * 16;

  // Q tile: 128 rows x 64 d -> padded LDS (rows r0, r0+64; both 32-d halves)
  {
    #pragma unroll
    for (int rr = 0; rr < 2; ++rr){
      const char* gq = (const char*)qb + (size_t)(bh*NS + q0 + r0 + rr*64)*128 + ch;
      uint4 qp0 = *(const uint4*)(gq);
      uint4 qp1 = *(const uint4*)(gq + 64);
      *(uint4*)((char*)smQ[0] + (r0 + rr*64)*(LROW*2) + ch) = qp0;
      *(uint4*)((char*)smQ[1] + (r0 + rr*64)*(LROW*2) + ch) = qp1;
    }
  }

  // K/V register prefetch (tile 0)
  const char* gk = (const char*)kb + ((size_t)bh*NS + r0)*128 + ch;
  const char* gv = (const char*)vb + ((size_t)(bh*ND + r0))*(NS*2) + ch;
  uint4 kp0 = *(const uint4*)(gk);
  uint4 kp1 = *(const uint4*)(gk + 64);
  uint4 vp0 = *(const uint4*)(gv);
  uint4 vp1 = *(const uint4*)(gv + 64);

  char* wK0 = (char*)smK[0] + r0*(LROW*2) + ch;
  char* wK1 = (char*)smK[1] + r0*(LROW*2) + ch;
  char* wV0 = (char*)smV[0] + r0*(LROW*2) + ch;
  char* wV1 = (char*)smV[1] + r0*(LROW*2) + ch;

  float m_i[2] = {-1e30f, -1e30f}, l_i[2] = {0.f, 0.f};
  f32x4 accO[2][4] = {};
  const int ntiles = (len + 63) >> 6;
  char* pRow = (char*)&smP[wave][0] + l16*(PROW*2);

  for (int t = 0; t < ntiles; ++t){
    __syncthreads();                       // prior readers done; prefetch vmcnt drains here
    *(uint4*)wK0 = kp0; *(uint4*)wK1 = kp1;
    *(uint4*)wV0 = vp0; *(uint4*)wV1 = vp1;
    __syncthreads();                       // writes visible
    if (t + 1 < ntiles){                   // prefetch t+1 (hidden behind 2 groups of compute)
      const char* nk = gk + (size_t)(t+1)*8192;
      const char* nv = gv + (size_t)(t+1)*128;
      kp0 = *(const uint4*)(nk); kp1 = *(const uint4*)(nk + 64);
      vp0 = *(const uint4*)(nv); vp1 = *(const uint4*)(nv + 64);
    }
    int key0 = t*64;

    #pragma unroll
    for (int g = 0; g < 2; ++g){
      // S^T = K_tile . Q^T  (per wave: 64 keys x 16 q-rows of group g)
      f32x4 accS[4] = {};
      #pragma unroll
      for (int kc = 0; kc < 2; ++kc){
        bf16x8 bq = *(const bf16x8*)&smQ[kc][(g*64 + wave*16 + l16)*LROW + quad*8];
        #pragma unroll
        for (int ni = 0; ni < 4; ++ni){
          bf16x8 ak = *(const bf16x8*)&smK[kc][(ni*16 + l16)*LROW + quad*8];
          accS[ni] = __builtin_amdgcn_mfma_f32_16x16x32_bf16(ak, bq, accS[ni], 0, 0, 0);
        }
      }

      // online softmax: lane owns q-row (l16); keys = key0 + ni*16 + quad*4 + r
      float mx = -3e38f;
      #pragma unroll
      for (int ni = 0; ni < 4; ++ni)
        #pragma unroll
        for (int r = 0; r < 4; ++r){
          int key = key0 + ni*16 + quad*4 + r;
          float x = (key < len) ? accS[ni][r] : -1e30f;
          accS[ni][r] = x;
          mx = fmaxf(mx, x);
        }
      mx = fmaxf(mx, __shfl_xor(mx, 16, 64));
      mx = fmaxf(mx, __shfl_xor(mx, 32, 64));
      float mnew = fmaxf(m_i[g], mx);
      float alpha = EXP2(m_i[g] - mnew);
      float sum = 0.f;
      #pragma unroll
      for (int ni = 0; ni < 4; ++ni){
        float p0 = EXP2(accS[ni][0] - mnew);
        float p1 = EXP2(accS[ni][1] - mnew);
        float p2 = EXP2(accS[ni][2] - mnew);
        float p3 = EXP2(accS[ni][3] - mnew);
        sum += (p0 + p1) + (p2 + p3);
        uint2 pr; pr.x = pack2bf(p0, p1); pr.y = pack2bf(p2, p3);
        *(uint2*)(pRow + ni*32 + quad*8) = pr;
      }
      sum += __shfl_xor(sum, 16, 64);
      sum += __shfl_xor(sum, 32, 64);
      l_i[g] = l_i[g] * alpha + sum;
      m_i[g] = mnew;
      #pragma unroll
      for (int di = 0; di < 4; ++di) accO[g][di] *= alpha;
      asm volatile("s_waitcnt lgkmcnt(0)" ::: "memory");

      // O^T += V^T_tile . P^T
      #pragma unroll
      for (int kc = 0; kc < 2; ++kc){
        bf16x8 bp = *(const bf16x8*)(pRow + kc*64 + quad*16);
        #pragma unroll
        for (int di = 0; di < 4; ++di){
          bf16x8 av = *(const bf16x8*)&smV[kc][(di*16 + l16)*LROW + quad*8];
          accO[g][di] = __builtin_amdgcn_mfma_f32_16x16x32_bf16(av, bp, accO[g][di], 0, 0, 0);
        }
      }
    }
  }

  // epilogue: both groups; lane owns q-row; d = di*16 + quad*4 (b64 stores)
  #pragma unroll
  for (int g = 0; g < 2; ++g){
    int q = q0 + g*64 + wave*16 + l16;
    float inv = (q < len) ? (1.0f / l_i[g]) : 0.f;
    size_t base = (size_t)(b*NS + q)*NE + h*ND;
    #pragma unroll
    for (int di = 0; di < 4; ++di){
      float v0 = accO[g][di][0]*inv, v1 = accO[g][di][1]*inv;
      float v2 = accO[g][di][2]*inv, v3 = accO[g][di][3]*inv;
      uint2 pr; pr.x = pack2bf(v0, v1); pr.y = pack2bf(v2, v3);
      *(uint2*)&ctx[base + di*16 + quad*4] = pr;
    }
  }
}

// ---------------- output projection GEMM: [8192,768] x [768,768]^T -> fp32, BK=64 ----------------
__global__ __launch_bounds__(256, 2) void gemm_out(
    const u16* __restrict__ A, const u16* __restrict__ Bw,
    const float* __restrict__ bias, float* __restrict__ out)
{
  __shared__ __align__(16) u16 smA[128*LRW];
  __shared__ __align__(16) u16 smB[128*LRW];
  const int tid = threadIdx.x;
  const int lane = tid & 63;
  const int wave = tid >> 6;
  const int quad = lane >> 4, l16 = lane & 15;
  const int wm = wave >> 1, wn = wave & 1;
  const int m0 = blockIdx.y * 128;
  const int n0 = blockIdx.x * 128;

  const int srow = tid >> 2;
  const int soff = (tid & 3) * 16;
  const char* gA = (const char*)A + ((size_t)(m0 + srow)*NE)*2 + soff;
  const char* gB = (const char*)Bw + ((size_t)(n0 + srow)*NE)*2 + soff;
  uint4 a00 = *(const uint4*)(gA);
  uint4 a01 = *(const uint4*)(gA + 64);
  uint4 a10 = *(const uint4*)(gA + (size_t)64*NE*2);
  uint4 a11 = *(const uint4*)(gA + (size_t)64*NE*2 + 64);
  uint4 b00 = *(const uint4*)(gB);
  uint4 b01 = *(const uint4*)(gB + 64);
  uint4 b10 = *(const uint4*)(gB + (size_t)64*NE*2);
  uint4 b11 = *(const uint4*)(gB + (size_t)64*NE*2 + 64);
  char* lA = (char*)smA + srow*(LRW*2) + soff;
  char* lB = (char*)smB + srow*(LRW*2) + soff;

  f32x4 acc[4][4] = {};

  for (int kt = 0; kt < NE; kt += 64){
    __syncthreads();
    *(uint4*)lA = a00; *(uint4*)(lA + 64) = a01;
    *(uint4*)(lA + 64*LRW*2) = a10; *(uint4*)(lA + 64*LRW*2 + 64) = a11;
    *(uint4*)lB = b00; *(uint4*)(lB + 64) = b01;
    *(uint4*)(lB + 64*LRW*2) = b10; *(uint4*)(lB + 64*LRW*2 + 64) = b11;
    __syncthreads();
    if (kt + 64 < NE){
      const char* nA = gA + (kt + 64)*2;
      const char* nB = gB + (kt + 64)*2;
      a00 = *(const uint4*)nA; a01 = *(const uint4*)(nA + 64);
      a10 = *(const uint4*)(nA + (size_t)64*NE*2); a11 = *(const uint4*)(nA + (size_t)64*NE*2 + 64);
      b00 = *(const uint4*)nB; b01 = *(const uint4*)(nB + 64);
      b10 = *(const uint4*)(nB + (size_t)64*NE*2); b11 = *(const uint4*)(nB + (size_t)64*NE*2 + 64);
    }
    #pragma unroll
    for (int kc = 0; kc < 2; ++kc){
      bf16x8 av[4], bv[4];
      #pragma unroll
      for (int i = 0; i < 4; ++i){
        av[i] = *(const bf16x8*)&smA[(wm*64 + i*16 + l16)*LRW + kc*32 + quad*8];
        bv[i] = *(const bf16x8*)&smB[(wn*64 + i*16 + l16)*LRW + kc*32 + quad*8];
      }
      #pragma unroll
      for (int mi = 0; mi < 4; ++mi)
        #pragma unroll
        for (int ni = 0; ni < 4; ++ni)
          acc[mi][ni] = __builtin_amdgcn_mfma_f32_16x16x32_bf16(bv[ni], av[mi], acc[mi][ni], 0, 0, 0);
    }
  }

  #pragma unroll
  for (int ni = 0; ni < 4; ++ni){
    int gcol0 = n0 + wn*64 + ni*16 + quad*4;
    float4 b4 = *(const float4*)&bias[gcol0];
    #pragma unroll
    for (int mi = 0; mi < 4; ++mi){
      int grow = m0 + wm*64 + mi*16 + l16;
      float4 o;
      o.x = acc[mi][ni][0] + b4.x; o.y = acc[mi][ni][1] + b4.y;
      o.z = acc[mi][ni][2] + b4.z; o.w = acc[mi][ni][3] + b4.w;
      *(float4*)&out[(size_t)grow*NE + gcol0] = o;
    }
  }
}

extern "C" void kernel_launch(void* const* d_in, const int* in_sizes, int n_in,
                              void* d_out, int out_size, void* d_ws, size_t ws_size,
                              hipStream_t stream)
{
  const float* x    = (const float*)d_in[0];
  const void*  mask = d_in[1];
  const float* wqkv = (const float*)d_in[2];
  const float* bqkv = (const float*)d_in[3];
  const float* wout = (const float*)d_in[4];
  const float* bout = (const float*)d_in[5];

  char* ws = (char*)d_ws;
  u16* xb    = (u16*)(ws + 0);
  u16* wqkvb = (u16*)(ws + 12582912);
  u16* woutb = (u16*)(ws + 16121856);
  u16* qbuf  = (u16*)(ws + 17301504);
  u16* kbuf  = (u16*)(ws + 29884416);
  u16* vbuf  = (u16*)(ws + 42467328);
  u16* ctxb  = (u16*)(ws + 55050240);
  int* lens  = (int*)(ws + 67633152);

  cvt3_kernel<<<8448, 256, 0, stream>>>(x, wqkv, wout, xb, wqkvb, woutb);
  lengths_kernel<<<1, 512, 0, stream>>>((const unsigned int*)mask, lens);
  gemm_qkv<<<dim3(18, 64), 256, 0, stream>>>(xb, wqkvb, bqkv, qbuf, kbuf, vbuf);
  attn_kernel<<<dim3(8, 96), 256, 0, stream>>>(qbuf, kbuf, vbuf, lens, ctxb);
  gemm_out<<<dim3(6, 64), 256, 0, stream>>>(ctxb, woutb, bout, (float*)d_out);
}

// Round 6
// 210.603 us; speedup vs baseline: 3.7269x; 1.0539x over previous
//
#include <hip/hip_runtime.h>

typedef short bf16x8 __attribute__((ext_vector_type(8)));
typedef float f32x4 __attribute__((ext_vector_type(4)));
typedef unsigned short u16;

#define NB 8
#define NS 1024
#define NE 768
#define NH 12
#define ND 64
#define QSCALE 0.18033688011112042f   // 0.125 * log2(e): scores land in log2 domain

__device__ __forceinline__ u16 f2bf(float f){
  unsigned u = __float_as_uint(f);
  u += 0x7fffu + ((u >> 16) & 1u);
  return (u16)(u >> 16);
}

// pack two fp32 -> two bf16 (round-half-up) in one u32 via v_perm
__device__ __forceinline__ unsigned pack2bf(float a, float b){
  unsigned ua = __float_as_uint(a) + 0x8000u;
  unsigned ub = __float_as_uint(b) + 0x8000u;
  return __builtin_amdgcn_perm(ub, ua, 0x07060302u);
}

#define EXP2(x) __builtin_amdgcn_exp2f(x)

// ---------------- fused fp32 -> bf16 convert (x, Wqkv, out_w in one launch) ----------------
__global__ void cvt3_kernel(const float* __restrict__ s0, const float* __restrict__ s1,
                            const float* __restrict__ s2,
                            u16* __restrict__ d0, u16* __restrict__ d1, u16* __restrict__ d2){
  const int n0 = 1572864, n1 = 442368, n2 = 147456;   // float4 counts
  int i = blockIdx.x * 256 + threadIdx.x;
  const float* s; u16* d; int j;
  if (i < n0){ s = s0; d = d0; j = i; }
  else if (i < n0 + n1){ s = s1; d = d1; j = i - n0; }
  else { s = s2; d = d2; j = i - n0 - n1; }
  float4 v = ((const float4*)s)[j];
  ushort4 o;
  o.x = f2bf(v.x); o.y = f2bf(v.y); o.z = f2bf(v.z); o.w = f2bf(v.w);
  ((ushort4*)d)[j] = o;
}

// ---------------- lengths from prefix mask (dtype auto-detect) ----------------
__global__ void lengths_kernel(const unsigned int* __restrict__ mi, int* __restrict__ lens){
  __shared__ int isByte;
  int tid = threadIdx.x;
  int any = 0;
  for (int i = tid; i < 2048; i += 512) any |= (mi[i] > 1u) ? 1 : 0;
  if (tid == 0) isByte = 0;
  __syncthreads();
  if (any) atomicOr(&isByte, 1);
  __syncthreads();
  int byteMode = isByte;
  int b = tid >> 6, lane = tid & 63;
  int cnt = 0;
  if (byteMode){
    const unsigned char* p = (const unsigned char*)mi;
    for (int j = 0; j < 16; ++j) cnt += p[b*NS + j*64 + lane] ? 1 : 0;
  } else {
    for (int j = 0; j < 16; ++j) cnt += mi[b*NS + j*64 + lane] ? 1 : 0;
  }
  for (int o = 1; o < 64; o <<= 1) cnt += __shfl_xor(cnt, o, 64);
  if (lane == 0) lens[b] = cnt;
}

// gemm LDS row stride (BK=64): 64 bf16 + 8 pad = 72 u16 = 144 B (granule stride 9: odd)
#define LRW 72

// ---------------- QKV projection GEMM: [8192,768] x [2304,768]^T, BK=64 ----------------
// reg-prefetch pipeline (8 uint4), 12 barrier pairs; per-block operand swap for packed stores
// (256,2): 256-reg budget. R3 lesson: (256,4) cap=128 spilled 2.7GB scratch.
__global__ __launch_bounds__(256, 2) void gemm_qkv(
    const u16* __restrict__ A, const u16* __restrict__ Bw,
    const float* __restrict__ bias,
    u16* __restrict__ qb, u16* __restrict__ kb, u16* __restrict__ vb)
{
  __shared__ __align__(16) u16 smA[128*LRW];
  __shared__ __align__(16) u16 smB[128*LRW];
  const int tid = threadIdx.x;
  const int lane = tid & 63;
  const int wave = tid >> 6;
  const int quad = lane >> 4, l16 = lane & 15;
  const int wm = wave >> 1, wn = wave & 1;
  const int m0 = blockIdx.y * 128;
  const int n0 = blockIdx.x * 128;
  const int which = blockIdx.x / 6;        // 0=q, 1=k, 2=v (uniform per block)

  // staging: thread covers rows srow/srow+64, 16B chunks at soff and soff+64 (BK=64 row = 128B)
  const int srow = tid >> 2;
  const int soff = (tid & 3) * 16;
  const char* gA = (const char*)A + ((size_t)(m0 + srow)*NE)*2 + soff;
  const char* gB = (const char*)Bw + ((size_t)(n0 + srow)*NE)*2 + soff;
  uint4 a00 = *(const uint4*)(gA);
  uint4 a01 = *(const uint4*)(gA + 64);
  uint4 a10 = *(const uint4*)(gA + (size_t)64*NE*2);
  uint4 a11 = *(const uint4*)(gA + (size_t)64*NE*2 + 64);
  uint4 b00 = *(const uint4*)(gB);
  uint4 b01 = *(const uint4*)(gB + 64);
  uint4 b10 = *(const uint4*)(gB + (size_t)64*NE*2);
  uint4 b11 = *(const uint4*)(gB + (size_t)64*NE*2 + 64);
  char* lA = (char*)smA + srow*(LRW*2) + soff;
  char* lB = (char*)smB + srow*(LRW*2) + soff;

  f32x4 acc[4][4] = {};

  for (int kt = 0; kt < NE; kt += 64){
    __syncthreads();                 // prior readers done (vmcnt for prefetch drains here)
    *(uint4*)lA = a00; *(uint4*)(lA + 64) = a01;
    *(uint4*)(lA + 64*LRW*2) = a10; *(uint4*)(lA + 64*LRW*2 + 64) = a11;
    *(uint4*)lB = b00; *(uint4*)(lB + 64) = b01;
    *(uint4*)(lB + 64*LRW*2) = b10; *(uint4*)(lB + 64*LRW*2 + 64) = b11;
    __syncthreads();
    if (kt + 64 < NE){               // prefetch next K-tile (hidden behind 32 MFMA)
      const char* nA = gA + (kt + 64)*2;
      const char* nB = gB + (kt + 64)*2;
      a00 = *(const uint4*)nA; a01 = *(const uint4*)(nA + 64);
      a10 = *(const uint4*)(nA + (size_t)64*NE*2); a11 = *(const uint4*)(nA + (size_t)64*NE*2 + 64);
      b00 = *(const uint4*)nB; b01 = *(const uint4*)(nB + 64);
      b10 = *(const uint4*)(nB + (size_t)64*NE*2); b11 = *(const uint4*)(nB + (size_t)64*NE*2 + 64);
    }
    #pragma unroll
    for (int kc = 0; kc < 2; ++kc){
      bf16x8 av[4], bv[4];
      #pragma unroll
      for (int i = 0; i < 4; ++i){
        av[i] = *(const bf16x8*)&smA[(wm*64 + i*16 + l16)*LRW + kc*32 + quad*8];
        bv[i] = *(const bf16x8*)&smB[(wn*64 + i*16 + l16)*LRW + kc*32 + quad*8];
      }
      if (which < 2){
        #pragma unroll
        for (int mi = 0; mi < 4; ++mi)
          #pragma unroll
          for (int ni = 0; ni < 4; ++ni)
            acc[mi][ni] = __builtin_amdgcn_mfma_f32_16x16x32_bf16(bv[ni], av[mi], acc[mi][ni], 0, 0, 0);
      } else {
        #pragma unroll
        for (int mi = 0; mi < 4; ++mi)
          #pragma unroll
          for (int ni = 0; ni < 4; ++ni)
            acc[mi][ni] = __builtin_amdgcn_mfma_f32_16x16x32_bf16(av[mi], bv[ni], acc[mi][ni], 0, 0, 0);
      }
    }
  }

  if (which < 2){
    // swapped: m on l16, n on (quad,r) -> 4 consecutive d per lane
    u16* dst = (which == 0) ? qb : kb;
    const float sc = (which == 0) ? QSCALE : 1.0f;
    #pragma unroll
    for (int ni = 0; ni < 4; ++ni){
      int gcol0 = n0 + wn*64 + ni*16 + quad*4;
      int rem = gcol0 - which*NE;
      int hh = rem >> 6, dd0 = rem & 63;
      float4 b4 = *(const float4*)&bias[gcol0];
      #pragma unroll
      for (int mi = 0; mi < 4; ++mi){
        int grow = m0 + wm*64 + mi*16 + l16;
        int bb = grow >> 10, ss = grow & 1023;
        int bh = bb*NH + hh;
        float v0 = (acc[mi][ni][0] + b4.x)*sc, v1 = (acc[mi][ni][1] + b4.y)*sc;
        float v2 = (acc[mi][ni][2] + b4.z)*sc, v3 = (acc[mi][ni][3] + b4.w)*sc;
        uint2 pr; pr.x = pack2bf(v0, v1); pr.y = pack2bf(v2, v3);
        *(uint2*)&dst[((size_t)bh*NS + ss)*ND + dd0] = pr;
      }
    }
  } else {
    // normal: n on l16, m(=s) on (quad,r) -> 4 consecutive s per lane in (b,h,d,s)
    #pragma unroll
    for (int ni = 0; ni < 4; ++ni){
      int gcol = n0 + wn*64 + ni*16 + l16;
      int rem = gcol - 2*NE;
      int hh = rem >> 6, dd = rem & 63;
      float bval = bias[gcol];
      #pragma unroll
      for (int mi = 0; mi < 4; ++mi){
        int grow0 = m0 + wm*64 + mi*16 + quad*4;
        int bb = grow0 >> 10, ss0 = grow0 & 1023;
        int bh = bb*NH + hh;
        float v0 = acc[mi][ni][0] + bval, v1 = acc[mi][ni][1] + bval;
        float v2 = acc[mi][ni][2] + bval, v3 = acc[mi][ni][3] + bval;
        uint2 pr; pr.x = pack2bf(v0, v1); pr.y = pack2bf(v2, v3);
        *(uint2*)&vb[((size_t)bh*ND + dd)*NS + ss0] = pr;
      }
    }
  }
}

// ---------------- flash attention: 64-row Q tile, single-barrier ping-pong K/V ----------------
// grid (bh=96, qtile=16): same-bh blocks spaced 96 (96%8==0) -> same XCD -> K/V L2-local.
// attn LDS rows: 64B unpadded (2-way bank aliasing = free); P row 144B (16B-aligned, 2-way free)
#define PROW 72
__global__ __launch_bounds__(256, 3) void attn_kernel(
    const u16* __restrict__ qb, const u16* __restrict__ kb,
    const u16* __restrict__ vb, const int* __restrict__ lens,
    u16* __restrict__ ctx)
{
  __shared__ __align__(16) u16 smQ[2][64*32];
  __shared__ __align__(16) u16 smK[2][2][64*32];   // [buf][kc]
  __shared__ __align__(16) u16 smV[2][2][64*32];
  __shared__ __align__(16) u16 smP[4][16*PROW];

  const int tid = threadIdx.x, lane = tid & 63, wave = tid >> 6;
  const int quad = lane >> 4, l16 = lane & 15;
  const int bh = blockIdx.x;
  const int b = bh / NH;
  const int h = bh - b*NH;
  const int q0 = blockIdx.y * 64;
  const int len = lens[b];

  const int r0 = tid >> 2;
  const int ch = (tid & 3) * 16;

  // Q tile: 64 rows x 64 d -> LDS (two 32-d halves)
  {
    const char* gq = (const char*)qb + (size_t)(bh*NS + q0 + r0)*128 + ch;
    uint4 qp0 = *(const uint4*)(gq);
    uint4 qp1 = *(const uint4*)(gq + 64);
    *(uint4*)((char*)smQ[0] + r0*64 + ch) = qp0;
    *(uint4*)((char*)smQ[1] + r0*64 + ch) = qp1;
  }

  // K/V prefetch + stage tile 0 into buf 0
  const char* gk = (const char*)kb + ((size_t)bh*NS + r0)*128 + ch;
  const char* gv = (const char*)vb + ((size_t)(bh*ND + r0))*(NS*2) + ch;
  {
    uint4 kp0 = *(const uint4*)(gk);
    uint4 kp1 = *(const uint4*)(gk + 64);
    uint4 vp0 = *(const uint4*)(gv);
    uint4 vp1 = *(const uint4*)(gv + 64);
    *(uint4*)((char*)smK[0][0] + r0*64 + ch) = kp0;
    *(uint4*)((char*)smK[0][1] + r0*64 + ch) = kp1;
    *(uint4*)((char*)smV[0][0] + r0*64 + ch) = vp0;
    *(uint4*)((char*)smV[0][1] + r0*64 + ch) = vp1;
  }
  __syncthreads();     // Q + tile0 visible

  float m_i = -1e30f, l_i = 0.f;
  f32x4 accO[4] = {};
  const int ntiles = (len + 63) >> 6;
  char* pRow = (char*)&smP[wave][0] + l16*(PROW*2);

  uint4 kp0, kp1, vp0, vp1;
  for (int t = 0; t < ntiles; ++t){
    const int buf = t & 1;
    if (t + 1 < ntiles){                   // issue prefetch t+1 (consumed after compute)
      const char* nk = gk + (size_t)(t+1)*8192;
      const char* nv = gv + (size_t)(t+1)*128;
      kp0 = *(const uint4*)(nk); kp1 = *(const uint4*)(nk + 64);
      vp0 = *(const uint4*)(nv); vp1 = *(const uint4*)(nv + 64);
    }

    // S^T = K_tile . Q^T  (per wave: 64 keys x 16 q-rows)
    f32x4 accS[4] = {};
    #pragma unroll
    for (int kc = 0; kc < 2; ++kc){
      bf16x8 bq = *(const bf16x8*)&smQ[kc][(wave*16 + l16)*32 + quad*8];
      #pragma unroll
      for (int ni = 0; ni < 4; ++ni){
        bf16x8 ak = *(const bf16x8*)&smK[buf][kc][(ni*16 + l16)*32 + quad*8];
        accS[ni] = __builtin_amdgcn_mfma_f32_16x16x32_bf16(ak, bq, accS[ni], 0, 0, 0);
      }
    }

    // online softmax: lane owns q-row (l16); keys = key0 + ni*16 + quad*4 + r
    int key0 = t*64;
    float mx = -3e38f;
    if (key0 + 64 <= len){                 // full tile: no masking (wave-uniform)
      #pragma unroll
      for (int ni = 0; ni < 4; ++ni)
        #pragma unroll
        for (int r = 0; r < 4; ++r) mx = fmaxf(mx, accS[ni][r]);
    } else {
      #pragma unroll
      for (int ni = 0; ni < 4; ++ni)
        #pragma unroll
        for (int r = 0; r < 4; ++r){
          int key = key0 + ni*16 + quad*4 + r;
          float x = (key < len) ? accS[ni][r] : -1e30f;
          accS[ni][r] = x;
          mx = fmaxf(mx, x);
        }
    }
    mx = fmaxf(mx, __shfl_xor(mx, 16, 64));
    mx = fmaxf(mx, __shfl_xor(mx, 32, 64));
    float mnew = fmaxf(m_i, mx);
    float alpha = EXP2(m_i - mnew);
    float sum = 0.f;
    #pragma unroll
    for (int ni = 0; ni < 4; ++ni){
      float p0 = EXP2(accS[ni][0] - mnew);
      float p1 = EXP2(accS[ni][1] - mnew);
      float p2 = EXP2(accS[ni][2] - mnew);
      float p3 = EXP2(accS[ni][3] - mnew);
      sum += (p0 + p1) + (p2 + p3);
      uint2 pr; pr.x = pack2bf(p0, p1); pr.y = pack2bf(p2, p3);
      *(uint2*)(pRow + ni*32 + quad*8) = pr;
    }
    sum += __shfl_xor(sum, 16, 64);
    sum += __shfl_xor(sum, 32, 64);
    l_i = l_i * alpha + sum;
    m_i = mnew;
    #pragma unroll
    for (int di = 0; di < 4; ++di) accO[di] *= alpha;
    asm volatile("s_waitcnt lgkmcnt(0)" ::: "memory");

    // O^T += V^T_tile . P^T
    #pragma unroll
    for (int kc = 0; kc < 2; ++kc){
      bf16x8 bp = *(const bf16x8*)(pRow + kc*64 + quad*16);
      #pragma unroll
      for (int di = 0; di < 4; ++di){
        bf16x8 av = *(const bf16x8*)&smV[buf][kc][(di*16 + l16)*32 + quad*8];
        accO[di] = __builtin_amdgcn_mfma_f32_16x16x32_bf16(av, bp, accO[di], 0, 0, 0);
      }
    }

    if (t + 1 < ntiles){                   // stage t+1 into other buf; ONE barrier per tile
      const int nbuf = 1 - buf;
      *(uint4*)((char*)smK[nbuf][0] + r0*64 + ch) = kp0;
      *(uint4*)((char*)smK[nbuf][1] + r0*64 + ch) = kp1;
      *(uint4*)((char*)smV[nbuf][0] + r0*64 + ch) = vp0;
      *(uint4*)((char*)smV[nbuf][1] + r0*64 + ch) = vp1;
      __syncthreads();
    }
  }

  // epilogue: lane owns q-row; d = di*16 + quad*4 + r (4 consecutive -> b64 store)
  int q = q0 + wave*16 + l16;
  float inv = (q < len) ? (1.0f / l_i) : 0.f;
  size_t base = (size_t)(b*NS + q)*NE + h*ND;
  #pragma unroll
  for (int di = 0; di < 4; ++di){
    float v0 = accO[di][0]*inv, v1 = accO[di][1]*inv;
    float v2 = accO[di][2]*inv, v3 = accO[di][3]*inv;
    uint2 pr; pr.x = pack2bf(v0, v1); pr.y = pack2bf(v2, v3);
    *(uint2*)&ctx[base + di*16 + quad*4] = pr;
  }
}

// ---------------- output projection GEMM: [8192,768] x [768,768]^T -> fp32, BK=64 ----------------
__global__ __launch_bounds__(256, 2) void gemm_out(
    const u16* __restrict__ A, const u16* __restrict__ Bw,
    const float* __restrict__ bias, float* __restrict__ out)
{
  __shared__ __align__(16) u16 smA[128*LRW];
  __shared__ __align__(16) u16 smB[128*LRW];
  const int tid = threadIdx.x;
  const int lane = tid & 63;
  const int wave = tid >> 6;
  const int quad = lane >> 4, l16 = lane & 15;
  const int wm = wave >> 1, wn = wave & 1;
  const int m0 = blockIdx.y * 128;
  const int n0 = blockIdx.x * 128;

  const int srow = tid >> 2;
  const int soff = (tid & 3) * 16;
  const char* gA = (const char*)A + ((size_t)(m0 + srow)*NE)*2 + soff;
  const char* gB = (const char*)Bw + ((size_t)(n0 + srow)*NE)*2 + soff;
  uint4 a00 = *(const uint4*)(gA);
  uint4 a01 = *(const uint4*)(gA + 64);
  uint4 a10 = *(const uint4*)(gA + (size_t)64*NE*2);
  uint4 a11 = *(const uint4*)(gA + (size_t)64*NE*2 + 64);
  uint4 b00 = *(const uint4*)(gB);
  uint4 b01 = *(const uint4*)(gB + 64);
  uint4 b10 = *(const uint4*)(gB + (size_t)64*NE*2);
  uint4 b11 = *(const uint4*)(gB + (size_t)64*NE*2 + 64);
  char* lA = (char*)smA + srow*(LRW*2) + soff;
  char* lB = (char*)smB + srow*(LRW*2) + soff;

  f32x4 acc[4][4] = {};

  for (int kt = 0; kt < NE; kt += 64){
    __syncthreads();
    *(uint4*)lA = a00; *(uint4*)(lA + 64) = a01;
    *(uint4*)(lA + 64*LRW*2) = a10; *(uint4*)(lA + 64*LRW*2 + 64) = a11;
    *(uint4*)lB = b00; *(uint4*)(lB + 64) = b01;
    *(uint4*)(lB + 64*LRW*2) = b10; *(uint4*)(lB + 64*LRW*2 + 64) = b11;
    __syncthreads();
    if (kt + 64 < NE){
      const char* nA = gA + (kt + 64)*2;
      const char* nB = gB + (kt + 64)*2;
      a00 = *(const uint4*)nA; a01 = *(const uint4*)(nA + 64);
      a10 = *(const uint4*)(nA + (size_t)64*NE*2); a11 = *(const uint4*)(nA + (size_t)64*NE*2 + 64);
      b00 = *(const uint4*)nB; b01 = *(const uint4*)(nB + 64);
      b10 = *(const uint4*)(nB + (size_t)64*NE*2); b11 = *(const uint4*)(nB + (size_t)64*NE*2 + 64);
    }
    #pragma unroll
    for (int kc = 0; kc < 2; ++kc){
      bf16x8 av[4], bv[4];
      #pragma unroll
      for (int i = 0; i < 4; ++i){
        av[i] = *(const bf16x8*)&smA[(wm*64 + i*16 + l16)*LRW + kc*32 + quad*8];
        bv[i] = *(const bf16x8*)&smB[(wn*64 + i*16 + l16)*LRW + kc*32 + quad*8];
      }
      #pragma unroll
      for (int mi = 0; mi < 4; ++mi)
        #pragma unroll
        for (int ni = 0; ni < 4; ++ni)
          acc[mi][ni] = __builtin_amdgcn_mfma_f32_16x16x32_bf16(bv[ni], av[mi], acc[mi][ni], 0, 0, 0);
    }
  }

  #pragma unroll
  for (int ni = 0; ni < 4; ++ni){
    int gcol0 = n0 + wn*64 + ni*16 + quad*4;
    float4 b4 = *(const float4*)&bias[gcol0];
    #pragma unroll
    for (int mi = 0; mi < 4; ++mi){
      int grow = m0 + wm*64 + mi*16 + l16;
      float4 o;
      o.x = acc[mi][ni][0] + b4.x; o.y = acc[mi][ni][1] + b4.y;
      o.z = acc[mi][ni][2] + b4.z; o.w = acc[mi][ni][3] + b4.w;
      *(float4*)&out[(size_t)grow*NE + gcol0] = o;
    }
  }
}

extern "C" void kernel_launch(void* const* d_in, const int* in_sizes, int n_in,
                              void* d_out, int out_size, void* d_ws, size_t ws_size,
                              hipStream_t stream)
{
  const float* x    = (const float*)d_in[0];
  const void*  mask = d_in[1];
  const float* wqkv = (const float*)d_in[2];
  const float* bqkv = (const float*)d_in[3];
  const float* wout = (const float*)d_in[4];
  const float* bout = (const float*)d_in[5];

  char* ws = (char*)d_ws;
  u16* xb    = (u16*)(ws + 0);
  u16* wqkvb = (u16*)(ws + 12582912);
  u16* woutb = (u16*)(ws + 16121856);
  u16* qbuf  = (u16*)(ws + 17301504);
  u16* kbuf  = (u16*)(ws + 29884416);
  u16* vbuf  = (u16*)(ws + 42467328);
  u16* ctxb  = (u16*)(ws + 55050240);
  int* lens  = (int*)(ws + 67633152);

  cvt3_kernel<<<8448, 256, 0, stream>>>(x, wqkv, wout, xb, wqkvb, woutb);
  lengths_kernel<<<1, 512, 0, stream>>>((const unsigned int*)mask, lens);
  gemm_qkv<<<dim3(18, 64), 256, 0, stream>>>(xb, wqkvb, bqkv, qbuf, kbuf, vbuf);
  attn_kernel<<<dim3(96, 16), 256, 0, stream>>>(qbuf, kbuf, vbuf, lens, ctxb);
  gemm_out<<<dim3(6, 64), 256, 0, stream>>>(ctxb, woutb, bout, (float*)d_out);
}

// Round 7
// 200.880 us; speedup vs baseline: 3.9073x; 1.0484x over previous
//
#include <hip/hip_runtime.h>

typedef short bf16x8 __attribute__((ext_vector_type(8)));
typedef float f32x4 __attribute__((ext_vector_type(4)));
typedef unsigned short u16;

#define NB 8
#define NS 1024
#define NE 768
#define NH 12
#define ND 64
#define QSCALE 0.18033688011112042f   // 0.125 * log2(e): scores land in log2 domain

__device__ __forceinline__ u16 f2bf(float f){
  unsigned u = __float_as_uint(f);
  u += 0x7fffu + ((u >> 16) & 1u);
  return (u16)(u >> 16);
}

// pack two fp32 -> two bf16 (round-half-up) in one u32 via v_perm
__device__ __forceinline__ unsigned pack2bf(float a, float b){
  unsigned ua = __float_as_uint(a) + 0x8000u;
  unsigned ub = __float_as_uint(b) + 0x8000u;
  return __builtin_amdgcn_perm(ub, ua, 0x07060302u);
}

#define EXP2(x) __builtin_amdgcn_exp2f(x)

// ---------------- fused fp32 -> bf16 convert (x, Wqkv, out_w in one launch) ----------------
__global__ void cvt3_kernel(const float* __restrict__ s0, const float* __restrict__ s1,
                            const float* __restrict__ s2,
                            u16* __restrict__ d0, u16* __restrict__ d1, u16* __restrict__ d2){
  const int n0 = 1572864, n1 = 442368, n2 = 147456;   // float4 counts
  int i = blockIdx.x * 256 + threadIdx.x;
  const float* s; u16* d; int j;
  if (i < n0){ s = s0; d = d0; j = i; }
  else if (i < n0 + n1){ s = s1; d = d1; j = i - n0; }
  else { s = s2; d = d2; j = i - n0 - n1; }
  float4 v = ((const float4*)s)[j];
  ushort4 o;
  o.x = f2bf(v.x); o.y = f2bf(v.y); o.z = f2bf(v.z); o.w = f2bf(v.w);
  ((ushort4*)d)[j] = o;
}

// ---------------- lengths from prefix mask (dtype auto-detect) ----------------
__global__ void lengths_kernel(const unsigned int* __restrict__ mi, int* __restrict__ lens){
  __shared__ int isByte;
  int tid = threadIdx.x;
  int any = 0;
  for (int i = tid; i < 2048; i += 512) any |= (mi[i] > 1u) ? 1 : 0;
  if (tid == 0) isByte = 0;
  __syncthreads();
  if (any) atomicOr(&isByte, 1);
  __syncthreads();
  int byteMode = isByte;
  int b = tid >> 6, lane = tid & 63;
  int cnt = 0;
  if (byteMode){
    const unsigned char* p = (const unsigned char*)mi;
    for (int j = 0; j < 16; ++j) cnt += p[b*NS + j*64 + lane] ? 1 : 0;
  } else {
    for (int j = 0; j < 16; ++j) cnt += mi[b*NS + j*64 + lane] ? 1 : 0;
  }
  for (int o = 1; o < 64; o <<= 1) cnt += __shfl_xor(cnt, o, 64);
  if (lane == 0) lens[b] = cnt;
}

// gemm LDS row stride (BK=64): 64 bf16 + 8 pad = 72 u16 = 144 B (granule stride 9: odd)
#define LRW 72

// ---------------- QKV projection GEMM: [8192,768] x [2304,768]^T, BK=64 ----------------
// reg-prefetch pipeline (8 uint4), 12 barrier pairs; per-block operand swap for packed stores
// (256,2): 256-reg budget. R3 lesson: (256,4) cap=128 spilled 2.7GB scratch.
__global__ __launch_bounds__(256, 2) void gemm_qkv(
    const u16* __restrict__ A, const u16* __restrict__ Bw,
    const float* __restrict__ bias,
    u16* __restrict__ qb, u16* __restrict__ kb, u16* __restrict__ vb)
{
  __shared__ __align__(16) u16 smA[128*LRW];
  __shared__ __align__(16) u16 smB[128*LRW];
  const int tid = threadIdx.x;
  const int lane = tid & 63;
  const int wave = tid >> 6;
  const int quad = lane >> 4, l16 = lane & 15;
  const int wm = wave >> 1, wn = wave & 1;
  const int m0 = blockIdx.y * 128;
  const int n0 = blockIdx.x * 128;
  const int which = blockIdx.x / 6;        // 0=q, 1=k, 2=v (uniform per block)

  const int srow = tid >> 2;
  const int soff = (tid & 3) * 16;
  const char* gA = (const char*)A + ((size_t)(m0 + srow)*NE)*2 + soff;
  const char* gB = (const char*)Bw + ((size_t)(n0 + srow)*NE)*2 + soff;
  uint4 a00 = *(const uint4*)(gA);
  uint4 a01 = *(const uint4*)(gA + 64);
  uint4 a10 = *(const uint4*)(gA + (size_t)64*NE*2);
  uint4 a11 = *(const uint4*)(gA + (size_t)64*NE*2 + 64);
  uint4 b00 = *(const uint4*)(gB);
  uint4 b01 = *(const uint4*)(gB + 64);
  uint4 b10 = *(const uint4*)(gB + (size_t)64*NE*2);
  uint4 b11 = *(const uint4*)(gB + (size_t)64*NE*2 + 64);
  char* lA = (char*)smA + srow*(LRW*2) + soff;
  char* lB = (char*)smB + srow*(LRW*2) + soff;

  f32x4 acc[4][4] = {};

  for (int kt = 0; kt < NE; kt += 64){
    __syncthreads();                 // prior readers done (vmcnt for prefetch drains here)
    *(uint4*)lA = a00; *(uint4*)(lA + 64) = a01;
    *(uint4*)(lA + 64*LRW*2) = a10; *(uint4*)(lA + 64*LRW*2 + 64) = a11;
    *(uint4*)lB = b00; *(uint4*)(lB + 64) = b01;
    *(uint4*)(lB + 64*LRW*2) = b10; *(uint4*)(lB + 64*LRW*2 + 64) = b11;
    __syncthreads();
    if (kt + 64 < NE){               // prefetch next K-tile (hidden behind 32 MFMA)
      const char* nA = gA + (kt + 64)*2;
      const char* nB = gB + (kt + 64)*2;
      a00 = *(const uint4*)nA; a01 = *(const uint4*)(nA + 64);
      a10 = *(const uint4*)(nA + (size_t)64*NE*2); a11 = *(const uint4*)(nA + (size_t)64*NE*2 + 64);
      b00 = *(const uint4*)nB; b01 = *(const uint4*)(nB + 64);
      b10 = *(const uint4*)(nB + (size_t)64*NE*2); b11 = *(const uint4*)(nB + (size_t)64*NE*2 + 64);
    }
    #pragma unroll
    for (int kc = 0; kc < 2; ++kc){
      bf16x8 av[4], bv[4];
      #pragma unroll
      for (int i = 0; i < 4; ++i){
        av[i] = *(const bf16x8*)&smA[(wm*64 + i*16 + l16)*LRW + kc*32 + quad*8];
        bv[i] = *(const bf16x8*)&smB[(wn*64 + i*16 + l16)*LRW + kc*32 + quad*8];
      }
      if (which < 2){
        #pragma unroll
        for (int mi = 0; mi < 4; ++mi)
          #pragma unroll
          for (int ni = 0; ni < 4; ++ni)
            acc[mi][ni] = __builtin_amdgcn_mfma_f32_16x16x32_bf16(bv[ni], av[mi], acc[mi][ni], 0, 0, 0);
      } else {
        #pragma unroll
        for (int mi = 0; mi < 4; ++mi)
          #pragma unroll
          for (int ni = 0; ni < 4; ++ni)
            acc[mi][ni] = __builtin_amdgcn_mfma_f32_16x16x32_bf16(av[mi], bv[ni], acc[mi][ni], 0, 0, 0);
      }
    }
  }

  if (which < 2){
    u16* dst = (which == 0) ? qb : kb;
    const float sc = (which == 0) ? QSCALE : 1.0f;
    #pragma unroll
    for (int ni = 0; ni < 4; ++ni){
      int gcol0 = n0 + wn*64 + ni*16 + quad*4;
      int rem = gcol0 - which*NE;
      int hh = rem >> 6, dd0 = rem & 63;
      float4 b4 = *(const float4*)&bias[gcol0];
      #pragma unroll
      for (int mi = 0; mi < 4; ++mi){
        int grow = m0 + wm*64 + mi*16 + l16;
        int bb = grow >> 10, ss = grow & 1023;
        int bh = bb*NH + hh;
        float v0 = (acc[mi][ni][0] + b4.x)*sc, v1 = (acc[mi][ni][1] + b4.y)*sc;
        float v2 = (acc[mi][ni][2] + b4.z)*sc, v3 = (acc[mi][ni][3] + b4.w)*sc;
        uint2 pr; pr.x = pack2bf(v0, v1); pr.y = pack2bf(v2, v3);
        *(uint2*)&dst[((size_t)bh*NS + ss)*ND + dd0] = pr;
      }
    }
  } else {
    #pragma unroll
    for (int ni = 0; ni < 4; ++ni){
      int gcol = n0 + wn*64 + ni*16 + l16;
      int rem = gcol - 2*NE;
      int hh = rem >> 6, dd = rem & 63;
      float bval = bias[gcol];
      #pragma unroll
      for (int mi = 0; mi < 4; ++mi){
        int grow0 = m0 + wm*64 + mi*16 + quad*4;
        int bb = grow0 >> 10, ss0 = grow0 & 1023;
        int bh = bb*NH + hh;
        float v0 = acc[mi][ni][0] + bval, v1 = acc[mi][ni][1] + bval;
        float v2 = acc[mi][ni][2] + bval, v3 = acc[mi][ni][3] + bval;
        uint2 pr; pr.x = pack2bf(v0, v1); pr.y = pack2bf(v2, v3);
        *(uint2*)&vb[((size_t)bh*ND + dd)*NS + ss0] = pr;
      }
    }
  }
}

// ---------------- flash attention ----------------
// grid (bh=96, qtile=16): same-bh blocks -> same XCD (96%8==0) -> K/V L2-local.
// K/V tiles: 64B rows, XOR chunk swizzle phys=((row>>1)+c)&3 -> conflict-free b128 r/w.
// Q fragments in registers (loop-invariant). P: 128B rows, chunk swizzle ((cc+l16)&7).
// LDS = 16K(K) + 16K(V) + 8K(P) = 40960 B -> 4 blocks/CU at (256,4); regs ~<128.
__global__ __launch_bounds__(256, 4) void attn_kernel(
    const u16* __restrict__ qb, const u16* __restrict__ kb,
    const u16* __restrict__ vb, const int* __restrict__ lens,
    u16* __restrict__ ctx)
{
  __shared__ __align__(16) u16 smK[2][2][64*32];   // [buf][kc]
  __shared__ __align__(16) u16 smV[2][2][64*32];
  __shared__ __align__(16) u16 smP[4][16*64];      // 128 B/row

  const int tid = threadIdx.x, lane = tid & 63, wave = tid >> 6;
  const int quad = lane >> 4, l16 = lane & 15;
  const int bh = blockIdx.x;
  const int b = bh / NH;
  const int h = bh - b*NH;
  const int q0 = blockIdx.y * 64;
  const int len = lens[b];

  // dead q-tile: all rows masked -> ctx rows are zero; skip the whole K-loop
  if (q0 >= len){
    int q = q0 + wave*16 + l16;
    size_t base = (size_t)(b*NS + q)*NE + h*ND;
    uint2 z; z.x = 0u; z.y = 0u;
    #pragma unroll
    for (int di = 0; di < 4; ++di)
      *(uint2*)&ctx[base + di*16 + quad*4] = z;
    return;
  }

  const int r0 = tid >> 2;
  const int ch = (tid & 3) * 16;                         // global 16B chunk
  const int wc = ((((r0 >> 1) + (tid & 3)) & 3) * 16);   // swizzled LDS chunk (write)
  const int pc8 = (((l16 >> 1) + quad) & 3) * 8;         // swizzled chunk (read, u16 units)

  // Q fragments straight from global (loop-invariant per wave)
  bf16x8 qf[2];
  {
    const char* gq = (const char*)qb + (size_t)(bh*NS + q0 + wave*16 + l16)*128 + quad*16;
    qf[0] = *(const bf16x8*)(gq);
    qf[1] = *(const bf16x8*)(gq + 64);
  }

  // K/V stage tile 0 into buf 0
  const char* gk = (const char*)kb + ((size_t)bh*NS + r0)*128 + ch;
  const char* gv = (const char*)vb + ((size_t)(bh*ND + r0))*(NS*2) + ch;
  {
    uint4 kp0 = *(const uint4*)(gk);
    uint4 kp1 = *(const uint4*)(gk + 64);
    uint4 vp0 = *(const uint4*)(gv);
    uint4 vp1 = *(const uint4*)(gv + 64);
    *(uint4*)((char*)smK[0][0] + r0*64 + wc) = kp0;
    *(uint4*)((char*)smK[0][1] + r0*64 + wc) = kp1;
    *(uint4*)((char*)smV[0][0] + r0*64 + wc) = vp0;
    *(uint4*)((char*)smV[0][1] + r0*64 + wc) = vp1;
  }
  __syncthreads();

  float m_i = -1e30f, l_i = 0.f;
  f32x4 accO[4] = {};
  const int ntiles = (len + 63) >> 6;
  char* pRow = (char*)&smP[wave][0] + l16*128;

  uint4 kp0, kp1, vp0, vp1;
  for (int t = 0; t < ntiles; ++t){
    const int buf = t & 1;
    if (t + 1 < ntiles){                   // issue prefetch t+1 (consumed after compute)
      const char* nk = gk + (size_t)(t+1)*8192;
      const char* nv = gv + (size_t)(t+1)*128;
      kp0 = *(const uint4*)(nk); kp1 = *(const uint4*)(nk + 64);
      vp0 = *(const uint4*)(nv); vp1 = *(const uint4*)(nv + 64);
    }

    // S^T = K_tile . Q^T  (per wave: 64 keys x 16 q-rows)
    f32x4 accS[4] = {};
    #pragma unroll
    for (int kc = 0; kc < 2; ++kc){
      #pragma unroll
      for (int ni = 0; ni < 4; ++ni){
        bf16x8 ak = *(const bf16x8*)&smK[buf][kc][(ni*16 + l16)*32 + pc8];
        accS[ni] = __builtin_amdgcn_mfma_f32_16x16x32_bf16(ak, qf[kc], accS[ni], 0, 0, 0);
      }
    }

    // online softmax: lane owns q-row (l16); keys = key0 + ni*16 + quad*4 + r
    int key0 = t*64;
    float mx = -3e38f;
    if (key0 + 64 <= len){                 // full tile: no masking (wave-uniform)
      #pragma unroll
      for (int ni = 0; ni < 4; ++ni)
        #pragma unroll
        for (int r = 0; r < 4; ++r) mx = fmaxf(mx, accS[ni][r]);
    } else {
      #pragma unroll
      for (int ni = 0; ni < 4; ++ni)
        #pragma unroll
        for (int r = 0; r < 4; ++r){
          int key = key0 + ni*16 + quad*4 + r;
          float x = (key < len) ? accS[ni][r] : -1e30f;
          accS[ni][r] = x;
          mx = fmaxf(mx, x);
        }
    }
    mx = fmaxf(mx, __shfl_xor(mx, 16, 64));
    mx = fmaxf(mx, __shfl_xor(mx, 32, 64));
    float mnew = fmaxf(m_i, mx);
    float alpha = EXP2(m_i - mnew);
    float sum = 0.f;
    #pragma unroll
    for (int ni = 0; ni < 4; ++ni){
      float p0 = EXP2(accS[ni][0] - mnew);
      float p1 = EXP2(accS[ni][1] - mnew);
      float p2 = EXP2(accS[ni][2] - mnew);
      float p3 = EXP2(accS[ni][3] - mnew);
      sum += (p0 + p1) + (p2 + p3);
      // logical byte off ni*32+quad*8 -> chunk cc=ni*2+(quad>>1), phys=((cc+l16)&7)*16+(quad&1)*8
      int cc = ni*2 + (quad >> 1);
      uint2 pr; pr.x = pack2bf(p0, p1); pr.y = pack2bf(p2, p3);
      *(uint2*)(pRow + (((cc + l16) & 7) * 16) + (quad & 1)*8) = pr;
    }
    sum += __shfl_xor(sum, 16, 64);
    sum += __shfl_xor(sum, 32, 64);
    l_i = l_i * alpha + sum;
    m_i = mnew;
    #pragma unroll
    for (int di = 0; di < 4; ++di) accO[di] *= alpha;
    asm volatile("s_waitcnt lgkmcnt(0)" ::: "memory");

    // O^T += V^T_tile . P^T  (bp: logical chunk cc=kc*4+quad, phys=((cc+l16)&7)*16)
    #pragma unroll
    for (int kc = 0; kc < 2; ++kc){
      bf16x8 bp = *(const bf16x8*)(pRow + ((((kc*4 + quad) + l16) & 7) * 16));
      #pragma unroll
      for (int di = 0; di < 4; ++di){
        bf16x8 av = *(const bf16x8*)&smV[buf][kc][(di*16 + l16)*32 + pc8];
        accO[di] = __builtin_amdgcn_mfma_f32_16x16x32_bf16(av, bp, accO[di], 0, 0, 0);
      }
    }

    if (t + 1 < ntiles){                   // stage t+1 into other buf; ONE barrier per tile
      const int nbuf = 1 - buf;
      *(uint4*)((char*)smK[nbuf][0] + r0*64 + wc) = kp0;
      *(uint4*)((char*)smK[nbuf][1] + r0*64 + wc) = kp1;
      *(uint4*)((char*)smV[nbuf][0] + r0*64 + wc) = vp0;
      *(uint4*)((char*)smV[nbuf][1] + r0*64 + wc) = vp1;
      __syncthreads();
    }
  }

  // epilogue: lane owns q-row; d = di*16 + quad*4 + r (4 consecutive -> b64 store)
  int q = q0 + wave*16 + l16;
  float inv = (q < len) ? (1.0f / l_i) : 0.f;
  size_t base = (size_t)(b*NS + q)*NE + h*ND;
  #pragma unroll
  for (int di = 0; di < 4; ++di){
    float v0 = accO[di][0]*inv, v1 = accO[di][1]*inv;
    float v2 = accO[di][2]*inv, v3 = accO[di][3]*inv;
    uint2 pr; pr.x = pack2bf(v0, v1); pr.y = pack2bf(v2, v3);
    *(uint2*)&ctx[base + di*16 + quad*4] = pr;
  }
}

// ---------------- output projection GEMM: [8192,768] x [768,768]^T -> fp32, BK=64 ----------------
__global__ __launch_bounds__(256, 2) void gemm_out(
    const u16* __restrict__ A, const u16* __restrict__ Bw,
    const float* __restrict__ bias, float* __restrict__ out)
{
  __shared__ __align__(16) u16 smA[128*LRW];
  __shared__ __align__(16) u16 smB[128*LRW];
  const int tid = threadIdx.x;
  const int lane = tid & 63;
  const int wave = tid >> 6;
  const int quad = lane >> 4, l16 = lane & 15;
  const int wm = wave >> 1, wn = wave & 1;
  const int m0 = blockIdx.y * 128;
  const int n0 = blockIdx.x * 128;

  const int srow = tid >> 2;
  const int soff = (tid & 3) * 16;
  const char* gA = (const char*)A + ((size_t)(m0 + srow)*NE)*2 + soff;
  const char* gB = (const char*)Bw + ((size_t)(n0 + srow)*NE)*2 + soff;
  uint4 a00 = *(const uint4*)(gA);
  uint4 a01 = *(const uint4*)(gA + 64);
  uint4 a10 = *(const uint4*)(gA + (size_t)64*NE*2);
  uint4 a11 = *(const uint4*)(gA + (size_t)64*NE*2 + 64);
  uint4 b00 = *(const uint4*)(gB);
  uint4 b01 = *(const uint4*)(gB + 64);
  uint4 b10 = *(const uint4*)(gB + (size_t)64*NE*2);
  uint4 b11 = *(const uint4*)(gB + (size_t)64*NE*2 + 64);
  char* lA = (char*)smA + srow*(LRW*2) + soff;
  char* lB = (char*)smB + srow*(LRW*2) + soff;

  f32x4 acc[4][4] = {};

  for (int kt = 0; kt < NE; kt += 64){
    __syncthreads();
    *(uint4*)lA = a00; *(uint4*)(lA + 64) = a01;
    *(uint4*)(lA + 64*LRW*2) = a10; *(uint4*)(lA + 64*LRW*2 + 64) = a11;
    *(uint4*)lB = b00; *(uint4*)(lB + 64) = b01;
    *(uint4*)(lB + 64*LRW*2) = b10; *(uint4*)(lB + 64*LRW*2 + 64) = b11;
    __syncthreads();
    if (kt + 64 < NE){
      const char* nA = gA + (kt + 64)*2;
      const char* nB = gB + (kt + 64)*2;
      a00 = *(const uint4*)nA; a01 = *(const uint4*)(nA + 64);
      a10 = *(const uint4*)(nA + (size_t)64*NE*2); a11 = *(const uint4*)(nA + (size_t)64*NE*2 + 64);
      b00 = *(const uint4*)nB; b01 = *(const uint4*)(nB + 64);
      b10 = *(const uint4*)(nB + (size_t)64*NE*2); b11 = *(const uint4*)(nB + (size_t)64*NE*2 + 64);
    }
    #pragma unroll
    for (int kc = 0; kc < 2; ++kc){
      bf16x8 av[4], bv[4];
      #pragma unroll
      for (int i = 0; i < 4; ++i){
        av[i] = *(const bf16x8*)&smA[(wm*64 + i*16 + l16)*LRW + kc*32 + quad*8];
        bv[i] = *(const bf16x8*)&smB[(wn*64 + i*16 + l16)*LRW + kc*32 + quad*8];
      }
      #pragma unroll
      for (int mi = 0; mi < 4; ++mi)
        #pragma unroll
        for (int ni = 0; ni < 4; ++ni)
          acc[mi][ni] = __builtin_amdgcn_mfma_f32_16x16x32_bf16(bv[ni], av[mi], acc[mi][ni], 0, 0, 0);
    }
  }

  #pragma unroll
  for (int ni = 0; ni < 4; ++ni){
    int gcol0 = n0 + wn*64 + ni*16 + quad*4;
    float4 b4 = *(const float4*)&bias[gcol0];
    #pragma unroll
    for (int mi = 0; mi < 4; ++mi){
      int grow = m0 + wm*64 + mi*16 + l16;
      float4 o;
      o.x = acc[mi][ni][0] + b4.x; o.y = acc[mi][ni][1] + b4.y;
      o.z = acc[mi][ni][2] + b4.z; o.w = acc[mi][ni][3] + b4.w;
      *(float4*)&out[(size_t)grow*NE + gcol0] = o;
    }
  }
}

extern "C" void kernel_launch(void* const* d_in, const int* in_sizes, int n_in,
                              void* d_out, int out_size, void* d_ws, size_t ws_size,
                              hipStream_t stream)
{
  const float* x    = (const float*)d_in[0];
  const void*  mask = d_in[1];
  const float* wqkv = (const float*)d_in[2];
  const float* bqkv = (const float*)d_in[3];
  const float* wout = (const float*)d_in[4];
  const float* bout = (const float*)d_in[5];

  char* ws = (char*)d_ws;
  u16* xb    = (u16*)(ws + 0);
  u16* wqkvb = (u16*)(ws + 12582912);
  u16* woutb = (u16*)(ws + 16121856);
  u16* qbuf  = (u16*)(ws + 17301504);
  u16* kbuf  = (u16*)(ws + 29884416);
  u16* vbuf  = (u16*)(ws + 42467328);
  u16* ctxb  = (u16*)(ws + 55050240);
  int* lens  = (int*)(ws + 67633152);

  cvt3_kernel<<<8448, 256, 0, stream>>>(x, wqkv, wout, xb, wqkvb, woutb);
  lengths_kernel<<<1, 512, 0, stream>>>((const unsigned int*)mask, lens);
  gemm_qkv<<<dim3(18, 64), 256, 0, stream>>>(xb, wqkvb, bqkv, qbuf, kbuf, vbuf);
  attn_kernel<<<dim3(96, 16), 256, 0, stream>>>(qbuf, kbuf, vbuf, lens, ctxb);
  gemm_out<<<dim3(6, 64), 256, 0, stream>>>(ctxb, woutb, bout, (float*)d_out);
}